// Round 8
// baseline (346.978 us; speedup 1.0000x reference)
//
#include <hip/hip_runtime.h>
#include <hip/hip_bf16.h>
#include <math.h>

#define HDIM 64
#define NN   100000
#define NE   1600000
#define TEMP 30.0f
#define LNEPS 1e-5f

// bucketing: 64 nodes per bucket, 8 XCD shards
#define GSH  6
#define GSZ  64
#define NB   1563          // ceil(NN/64)
#define NSH  8
#define NSB  (NSH * NB)    // 12504 counters (bucket-major, shard-minor)
#define E2   782           // edges per hist/scatter block (2048 blocks)
#define SCK  13            // counters per thread in single-block scan (1024*13 >= NSB)

typedef __attribute__((ext_vector_type(8))) short bf16x8;
typedef __attribute__((ext_vector_type(4))) float f32x4;

__device__ __forceinline__ short f2bf(float f) {
    __hip_bfloat16 b = __float2bfloat16(f);
    short s; __builtin_memcpy(&s, &b, 2); return s;
}
__device__ __forceinline__ unsigned pk2(float lo, float hi) {
    return (unsigned)(unsigned short)f2bf(lo) | ((unsigned)(unsigned short)f2bf(hi) << 16);
}
__device__ __forceinline__ float bf2f(unsigned u) {
    union { unsigned u; float f; } c; c.u = u << 16; return c.f;
}
__device__ __forceinline__ float sigmoidf_(float z) { return 1.0f / (1.0f + __expf(-z)); }

// ============ Pre kernel: per-NODE factorization of edge GEMM1 ============
// Pt[n] = h[n] @ We1_top + be1 ; Pb[n] = h[n] @ We1_bot   (bf16 rows, 128 B)
extern "C" __global__ void __launch_bounds__(256, 4)
pre_kernel(const float* __restrict__ h,
           const float* __restrict__ We1, const float* __restrict__ be1,
           unsigned short* __restrict__ Pt, unsigned short* __restrict__ Pb)
{
    __shared__ float fx[4][1024];
    const int tid  = threadIdx.x;
    const int wib  = tid >> 6;
    const int lane = tid & 63;
    const int e = lane & 15, g = lane >> 4;
    float* fb = &fx[wib][0];
    const int se = ((e & 1) << 4) | ((e >> 1) & 3);

    bf16x8 At[4][2], Ab[4][2];
    f32x4 b1r[4];
    #pragma unroll
    for (int t = 0; t < 4; ++t) {
        #pragma unroll
        for (int ks = 0; ks < 2; ++ks) {
            bf16x8 a, b;
            #pragma unroll
            for (int j = 0; j < 8; ++j) {
                a[j] = f2bf(We1[(32 * ks + 8 * g + j) * 64 + 16 * t + e]);
                b[j] = f2bf(We1[(64 + 32 * ks + 8 * g + j) * 64 + 16 * t + e]);
            }
            At[t][ks] = a; Ab[t][ks] = b;
        }
        #pragma unroll
        for (int r = 0; r < 4; ++r) b1r[t][r] = be1[16 * t + 4 * g + r];
    }

    const int gwid = blockIdx.x * 4 + wib;
    const int nw   = gridDim.x * 4;

    for (int tile = gwid; tile < NN / 16; tile += nw) {
        const int node = tile * 16 + e;

        bf16x8 B[2];
        #pragma unroll
        for (int ks = 0; ks < 2; ++ks) {
            const float4* p = (const float4*)(h + (size_t)node * 64 + ks * 32 + 8 * g);
            const float4 f0 = p[0], f1 = p[1];
            bf16x8 b;
            b[0] = f2bf(f0.x); b[1] = f2bf(f0.y); b[2] = f2bf(f0.z); b[3] = f2bf(f0.w);
            b[4] = f2bf(f1.x); b[5] = f2bf(f1.y); b[6] = f2bf(f1.z); b[7] = f2bf(f1.w);
            B[ks] = b;
        }

        f32x4 aT[4], aB[4];
        #pragma unroll
        for (int t = 0; t < 4; ++t) {
            aT[t] = b1r[t];
            aB[t] = (f32x4){0.f, 0.f, 0.f, 0.f};
            #pragma unroll
            for (int ks = 0; ks < 2; ++ks) {
                aT[t] = __builtin_amdgcn_mfma_f32_16x16x32_bf16(At[t][ks], B[ks], aT[t], 0, 0, 0);
                aB[t] = __builtin_amdgcn_mfma_f32_16x16x32_bf16(Ab[t][ks], B[ks], aB[t], 0, 0, 0);
            }
        }

        #pragma unroll
        for (int t = 0; t < 4; ++t)
            #pragma unroll
            for (int r = 0; r < 4; ++r)
                fb[e * 64 + ((16 * t + 4 * g + r) ^ se)] = aT[t][r];
        #pragma unroll
        for (int q = 0; q < 2; ++q) {
            const int row = q * 8 + (lane >> 3);
            const int sr  = ((row & 1) << 4) | ((row >> 1) & 3);
            const int c0  = (lane & 7) * 8;
            uint4 o;
            o.x = pk2(fb[row * 64 + ((c0 + 0) ^ sr)], fb[row * 64 + ((c0 + 1) ^ sr)]);
            o.y = pk2(fb[row * 64 + ((c0 + 2) ^ sr)], fb[row * 64 + ((c0 + 3) ^ sr)]);
            o.z = pk2(fb[row * 64 + ((c0 + 4) ^ sr)], fb[row * 64 + ((c0 + 5) ^ sr)]);
            o.w = pk2(fb[row * 64 + ((c0 + 6) ^ sr)], fb[row * 64 + ((c0 + 7) ^ sr)]);
            *(uint4*)((char*)Pt + (size_t)tile * 2048 + q * 1024 + lane * 16) = o;
        }

        #pragma unroll
        for (int t = 0; t < 4; ++t)
            #pragma unroll
            for (int r = 0; r < 4; ++r)
                fb[e * 64 + ((16 * t + 4 * g + r) ^ se)] = aB[t][r];
        #pragma unroll
        for (int q = 0; q < 2; ++q) {
            const int row = q * 8 + (lane >> 3);
            const int sr  = ((row & 1) << 4) | ((row >> 1) & 3);
            const int c0  = (lane & 7) * 8;
            uint4 o;
            o.x = pk2(fb[row * 64 + ((c0 + 0) ^ sr)], fb[row * 64 + ((c0 + 1) ^ sr)]);
            o.y = pk2(fb[row * 64 + ((c0 + 2) ^ sr)], fb[row * 64 + ((c0 + 3) ^ sr)]);
            o.z = pk2(fb[row * 64 + ((c0 + 4) ^ sr)], fb[row * 64 + ((c0 + 5) ^ sr)]);
            o.w = pk2(fb[row * 64 + ((c0 + 6) ^ sr)], fb[row * 64 + ((c0 + 7) ^ sr)]);
            *(uint4*)((char*)Pb + (size_t)tile * 2048 + q * 1024 + lane * 16) = o;
        }
    }
}

// ============ Bucket sort: sharded hist / single-block scan / scatter ============
extern "C" __global__ void __launch_bounds__(256)
hist2_kernel(const int* __restrict__ ei, int* __restrict__ cnt2)
{
    const int b  = blockIdx.x;                   // grid must be 2048
    const int i0 = b * E2;
    const int i1 = (i0 + E2 < NE) ? i0 + E2 : NE;
    const int sh = b & (NSH - 1);
    for (int i = i0 + threadIdx.x; i < i1; i += 256)
        atomicAdd(&cnt2[(ei[NE + i] >> GSH) * NSH + sh], 1);
}

// single-block scan over NSB counters (50 KB, L2-resident): one launch.
extern "C" __global__ void __launch_bounds__(1024)
scanM_kernel(const int* __restrict__ cnt2, int* __restrict__ off2, int* __restrict__ cur2)
{
    __shared__ int part[1024];
    const int t = threadIdx.x;
    int vals[SCK];
    int s = 0;
    #pragma unroll
    for (int j = 0; j < SCK; ++j) {
        const int idx = t * SCK + j;
        vals[j] = (idx < NSB) ? cnt2[idx] : 0;
        s += vals[j];
    }
    part[t] = s;
    __syncthreads();
    for (int off = 1; off < 1024; off <<= 1) {
        const int u = (t >= off) ? part[t - off] : 0;
        __syncthreads();
        part[t] += u;
        __syncthreads();
    }
    int run = part[t] - s;
    #pragma unroll
    for (int j = 0; j < SCK; ++j) {
        const int idx = t * SCK + j;
        if (idx < NSB) { off2[idx] = run; cur2[idx] = run; run += vals[j]; }
    }
}

extern "C" __global__ void __launch_bounds__(256)
scatter2_kernel(const int* __restrict__ ei, int* __restrict__ cur2,
                unsigned* __restrict__ sedge)
{
    const int b  = blockIdx.x;                   // grid must be 2048
    const int i0 = b * E2;
    const int i1 = (i0 + E2 < NE) ? i0 + E2 : NE;
    const int sh = b & (NSH - 1);
    for (int i = i0 + threadIdx.x; i < i1; i += 256) {
        const int s = ei[i];
        const int d = ei[NE + i];
        const int pos = atomicAdd(&cur2[(d >> GSH) * NSH + sh], 1);
        sedge[pos] = (unsigned)s | ((unsigned)(d & (GSZ - 1)) << 17);
    }
}

// ============ Bucket sort stage 2: per-bucket exact refinement ============
extern "C" __global__ void __launch_bounds__(256)
sort2_kernel(const unsigned* __restrict__ sedge, const int* __restrict__ off2,
             int2* __restrict__ spair)
{
    __shared__ int hist[GSZ], curs[GSZ];
    const int tid = threadIdx.x;
    const int b   = blockIdx.x;
    const int r0  = off2[b * NSH];
    const int r1  = (b == NB - 1) ? NE : off2[(b + 1) * NSH];

    if (tid < GSZ) hist[tid] = 0;
    __syncthreads();
    for (int i = r0 + tid; i < r1; i += 256)
        atomicAdd(&hist[(sedge[i] >> 17) & (GSZ - 1)], 1);
    __syncthreads();
    if (tid < GSZ) {                       // wave 0: parallel 64-bin exclusive scan
        const int v = hist[tid];
        int sum = v;
        #pragma unroll
        for (int off = 1; off < GSZ; off <<= 1) {
            const int u = __shfl_up(sum, off);
            if (tid >= off) sum += u;
        }
        curs[tid] = sum - v;               // exclusive prefix
    }
    __syncthreads();
    for (int i = r0 + tid; i < r1; i += 256) {
        const unsigned pk = sedge[i];
        const int dl = (pk >> 17) & (GSZ - 1);
        const int pos = r0 + atomicAdd(&curs[dl], 1);
        spair[pos] = make_int2((int)(pk & 0x1FFFFu), (b << GSH) | dl);
    }
}

// ============ Edge kernel (sorted): register-run accumulation, 4 blocks/CU ====
extern "C" __global__ void __launch_bounds__(256, 4)
edge_kernel_sorted(const unsigned short* __restrict__ Pt, const unsigned short* __restrict__ Pb,
                   const float* __restrict__ x, const int2* __restrict__ spair,
                   const float* __restrict__ We2, const float* __restrict__ be2,
                   const float* __restrict__ Winf, const float* __restrict__ binf,
                   float* __restrict__ mi)
{
    __shared__ float fx[4][1024];
    const int tid  = threadIdx.x;
    const int wib  = tid >> 6;
    const int lane = tid & 63;
    const int e = lane & 15, g = lane >> 4;
    float* fb = &fx[wib][0];
    const int se = ((e & 1) << 4) | ((e >> 1) & 3);

    bf16x8 A2[4][2];
    f32x4 b2r[4], wir[4];
    #pragma unroll
    for (int t = 0; t < 4; ++t) {
        #pragma unroll
        for (int ks = 0; ks < 2; ++ks) {
            bf16x8 a;
            #pragma unroll
            for (int j = 0; j < 8; ++j)
                a[j] = f2bf(We2[(32 * ks + 8 * g + j) * 64 + 16 * t + e]);
            A2[t][ks] = a;
        }
        #pragma unroll
        for (int r = 0; r < 4; ++r) {
            b2r[t][r] = be2[16 * t + 4 * g + r];
            wir[t][r] = Winf[16 * t + 4 * g + r];
        }
    }
    const float binf0 = binf[0];

    const int NT     = NE / 16;
    const int nwaves = gridDim.x * 4;
    const int gwid   = blockIdx.x * 4 + wib;
    const int chunk  = (NT + nwaves - 1) / nwaves;
    const int t0 = gwid * chunk;
    const int t1 = (t0 + chunk < NT) ? t0 + chunk : NT;

    float racc  = 0.f;   // running row accumulator, channel = lane
    int   rrow  = -1;    // wave-uniform current node id

    for (int tile = t0; tile < t1; ++tile) {
        const int eid = tile * 16 + e;
        const int2 sd = spair[eid];
        const int sN = sd.x;
        const int dN = sd.y;

        const float dx = x[dN * 3 + 0] - x[sN * 3 + 0];
        const float dy = x[dN * 3 + 1] - x[sN * 3 + 1];
        const float dz = x[dN * 3 + 2] - x[sN * 3 + 2];
        const float dsq = dx * dx + dy * dy + dz * dz;
        const float edis = sigmoidf_(TEMP / (sqrtf(dsq) + 1e-8f));

        bf16x8 B2[2];
        #pragma unroll
        for (int ks = 0; ks < 2; ++ks) {
            const uint4 ut = *(const uint4*)(Pt + (size_t)dN * 64 + 32 * ks + 8 * g);
            const uint4 ub = *(const uint4*)(Pb + (size_t)sN * 64 + 32 * ks + 8 * g);
            bf16x8 bb;
            unsigned tw, bw;
            tw = ut.x; bw = ub.x;
            bb[0] = f2bf(fmaxf(bf2f(tw & 0xffffu) + bf2f(bw & 0xffffu), 0.f));
            bb[1] = f2bf(fmaxf(bf2f(tw >> 16)     + bf2f(bw >> 16),     0.f));
            tw = ut.y; bw = ub.y;
            bb[2] = f2bf(fmaxf(bf2f(tw & 0xffffu) + bf2f(bw & 0xffffu), 0.f));
            bb[3] = f2bf(fmaxf(bf2f(tw >> 16)     + bf2f(bw >> 16),     0.f));
            tw = ut.z; bw = ub.z;
            bb[4] = f2bf(fmaxf(bf2f(tw & 0xffffu) + bf2f(bw & 0xffffu), 0.f));
            bb[5] = f2bf(fmaxf(bf2f(tw >> 16)     + bf2f(bw >> 16),     0.f));
            tw = ut.w; bw = ub.w;
            bb[6] = f2bf(fmaxf(bf2f(tw & 0xffffu) + bf2f(bw & 0xffffu), 0.f));
            bb[7] = f2bf(fmaxf(bf2f(tw >> 16)     + bf2f(bw >> 16),     0.f));
            B2[ks] = bb;
        }

        f32x4 acc2[4];
        #pragma unroll
        for (int t = 0; t < 4; ++t) {
            acc2[t] = b2r[t];
            #pragma unroll
            for (int ks = 0; ks < 2; ++ks)
                acc2[t] = __builtin_amdgcn_mfma_f32_16x16x32_bf16(A2[t][ks], B2[ks], acc2[t], 0, 0, 0);
        }

        float m[4][4];
        float p = 0.f;
        #pragma unroll
        for (int t = 0; t < 4; ++t)
            #pragma unroll
            for (int r = 0; r < 4; ++r) {
                m[t][r] = fmaxf(acc2[t][r], 0.f);
                p = fmaf(m[t][r], wir[t][r], p);
            }
        p += __shfl_xor(p, 16);
        p += __shfl_xor(p, 32);
        const float w = sigmoidf_((p + binf0) * edis);

        #pragma unroll
        for (int t = 0; t < 4; ++t)
            #pragma unroll
            for (int r = 0; r < 4; ++r)
                fb[e * 64 + ((16 * t + 4 * g + r) ^ se)] = m[t][r] * w;

        #pragma unroll
        for (int i = 0; i < 16; ++i) {
            const int row = __builtin_amdgcn_readlane(dN, i);
            const int si = ((i & 1) << 4) | ((i >> 1) & 3);
            const float v = fb[i * 64 + (lane ^ si)];
            if (row != rrow) {
                if (rrow >= 0) atomicAdd(mi + (size_t)rrow * 64 + lane, racc);
                rrow = row; racc = v;
            } else {
                racc += v;
            }
        }
    }
    if (rrow >= 0) atomicAdd(mi + (size_t)rrow * 64 + lane, racc);
}

// ============ Edge kernel (unsorted fallback, small-ws path) ============
extern "C" __global__ void __launch_bounds__(256, 2)
edge_kernel_unsorted(const unsigned short* __restrict__ Pt, const unsigned short* __restrict__ Pb,
                     const float* __restrict__ x, const int* __restrict__ ei,
                     const float* __restrict__ We2, const float* __restrict__ be2,
                     const float* __restrict__ Winf, const float* __restrict__ binf,
                     float* __restrict__ mi)
{
    __shared__ float fx[4][1024];
    const int tid  = threadIdx.x;
    const int wib  = tid >> 6;
    const int lane = tid & 63;
    const int e = lane & 15, g = lane >> 4;
    float* fb = &fx[wib][0];
    const int se = ((e & 1) << 4) | ((e >> 1) & 3);

    bf16x8 A2[4][2];
    f32x4 b2r[4], wir[4];
    #pragma unroll
    for (int t = 0; t < 4; ++t) {
        #pragma unroll
        for (int ks = 0; ks < 2; ++ks) {
            bf16x8 a;
            #pragma unroll
            for (int j = 0; j < 8; ++j)
                a[j] = f2bf(We2[(32 * ks + 8 * g + j) * 64 + 16 * t + e]);
            A2[t][ks] = a;
        }
        #pragma unroll
        for (int r = 0; r < 4; ++r) {
            b2r[t][r] = be2[16 * t + 4 * g + r];
            wir[t][r] = Winf[16 * t + 4 * g + r];
        }
    }
    const float binf0 = binf[0];

    const int gwid = blockIdx.x * 4 + wib;
    const int nw   = gridDim.x * 4;

    for (int tile = gwid; tile < NE / 16; tile += nw) {
        const int eid = tile * 16 + e;
        const int sN = ei[eid];
        const int dN = ei[NE + eid];

        const float dx = x[dN * 3 + 0] - x[sN * 3 + 0];
        const float dy = x[dN * 3 + 1] - x[sN * 3 + 1];
        const float dz = x[dN * 3 + 2] - x[sN * 3 + 2];
        const float dsq = dx * dx + dy * dy + dz * dz;
        const float edis = sigmoidf_(TEMP / (sqrtf(dsq) + 1e-8f));

        bf16x8 B2[2];
        #pragma unroll
        for (int ks = 0; ks < 2; ++ks) {
            const uint4 ut = *(const uint4*)(Pt + (size_t)dN * 64 + 32 * ks + 8 * g);
            const uint4 ub = *(const uint4*)(Pb + (size_t)sN * 64 + 32 * ks + 8 * g);
            bf16x8 bb;
            unsigned tw, bw;
            tw = ut.x; bw = ub.x;
            bb[0] = f2bf(fmaxf(bf2f(tw & 0xffffu) + bf2f(bw & 0xffffu), 0.f));
            bb[1] = f2bf(fmaxf(bf2f(tw >> 16)     + bf2f(bw >> 16),     0.f));
            tw = ut.y; bw = ub.y;
            bb[2] = f2bf(fmaxf(bf2f(tw & 0xffffu) + bf2f(bw & 0xffffu), 0.f));
            bb[3] = f2bf(fmaxf(bf2f(tw >> 16)     + bf2f(bw >> 16),     0.f));
            tw = ut.z; bw = ub.z;
            bb[4] = f2bf(fmaxf(bf2f(tw & 0xffffu) + bf2f(bw & 0xffffu), 0.f));
            bb[5] = f2bf(fmaxf(bf2f(tw >> 16)     + bf2f(bw >> 16),     0.f));
            tw = ut.w; bw = ub.w;
            bb[6] = f2bf(fmaxf(bf2f(tw & 0xffffu) + bf2f(bw & 0xffffu), 0.f));
            bb[7] = f2bf(fmaxf(bf2f(tw >> 16)     + bf2f(bw >> 16),     0.f));
            B2[ks] = bb;
        }

        f32x4 acc2[4];
        #pragma unroll
        for (int t = 0; t < 4; ++t) {
            acc2[t] = b2r[t];
            #pragma unroll
            for (int ks = 0; ks < 2; ++ks)
                acc2[t] = __builtin_amdgcn_mfma_f32_16x16x32_bf16(A2[t][ks], B2[ks], acc2[t], 0, 0, 0);
        }

        float m[4][4];
        float p = 0.f;
        #pragma unroll
        for (int t = 0; t < 4; ++t)
            #pragma unroll
            for (int r = 0; r < 4; ++r) {
                m[t][r] = fmaxf(acc2[t][r], 0.f);
                p = fmaf(m[t][r], wir[t][r], p);
            }
        p += __shfl_xor(p, 16);
        p += __shfl_xor(p, 32);
        const float w = sigmoidf_((p + binf0) * edis);

        #pragma unroll
        for (int t = 0; t < 4; ++t)
            #pragma unroll
            for (int r = 0; r < 4; ++r)
                fb[e * 64 + ((16 * t + 4 * g + r) ^ se)] = m[t][r] * w;

        #pragma unroll
        for (int i = 0; i < 16; ++i) {
            const int row = __shfl(dN, i);
            const int si = ((i & 1) << 4) | ((i >> 1) & 3);
            const float v = fb[i * 64 + (lane ^ si)];
            atomicAdd(mi + (size_t)row * 64 + lane, v);
        }
    }
}

// ============ Node kernel: same B2B MFMA + residual + LayerNorm =============
extern "C" __global__ void __launch_bounds__(256, 3)
node_kernel(const float* __restrict__ h, const float* __restrict__ mi_,
            const float* __restrict__ Wn1, const float* __restrict__ bn1,
            const float* __restrict__ Wn2, const float* __restrict__ bn2,
            const float* __restrict__ lng, const float* __restrict__ lnb,
            float* __restrict__ out)
{
    __shared__ unsigned xlds[4][16 * 32];
    const int tid  = threadIdx.x;
    const int wib  = tid >> 6;
    const int lane = tid & 63;
    const int e = lane & 15, g = lane >> 4;
    unsigned* tb = &xlds[wib][0];
    const int sw = (e & 7) << 2;

    bf16x8 A1[4][4], A2[4][2];
    f32x4 b1r[4], b2r[4], gr[4], br[4];
    #pragma unroll
    for (int t = 0; t < 4; ++t) {
        #pragma unroll
        for (int ks = 0; ks < 4; ++ks) {
            bf16x8 a;
            #pragma unroll
            for (int j = 0; j < 8; ++j)
                a[j] = f2bf(Wn1[(32 * ks + 8 * g + j) * 64 + 16 * t + e]);
            A1[t][ks] = a;
        }
        #pragma unroll
        for (int ks = 0; ks < 2; ++ks) {
            bf16x8 a;
            #pragma unroll
            for (int j = 0; j < 8; ++j)
                a[j] = f2bf(Wn2[(32 * ks + 8 * g + j) * 64 + 16 * t + e]);
            A2[t][ks] = a;
        }
        #pragma unroll
        for (int r = 0; r < 4; ++r) {
            b1r[t][r] = bn1[16 * t + 4 * g + r];
            b2r[t][r] = bn2[16 * t + 4 * g + r];
            gr[t][r]  = lng[16 * t + 4 * g + r];
            br[t][r]  = lnb[16 * t + 4 * g + r];
        }
    }

    const int gwid = blockIdx.x * 4 + wib;
    const int nw   = gridDim.x * 4;

    for (int tile = gwid; tile < NN / 16; tile += nw) {
        const int node = tile * 16 + e;

        bf16x8 B1[4];
        #pragma unroll
        for (int ks = 0; ks < 4; ++ks) {
            const float* srcp = (ks < 2) ? mi_ : h;
            const float4* p = (const float4*)(srcp + (size_t)node * 64 + (ks & 1) * 32 + 8 * g);
            const float4 f0 = p[0], f1 = p[1];
            bf16x8 b;
            b[0] = f2bf(f0.x); b[1] = f2bf(f0.y); b[2] = f2bf(f0.z); b[3] = f2bf(f0.w);
            b[4] = f2bf(f1.x); b[5] = f2bf(f1.y); b[6] = f2bf(f1.z); b[7] = f2bf(f1.w);
            B1[ks] = b;
        }

        f32x4 acc1[4];
        #pragma unroll
        for (int t = 0; t < 4; ++t) {
            acc1[t] = b1r[t];
            #pragma unroll
            for (int ks = 0; ks < 4; ++ks)
                acc1[t] = __builtin_amdgcn_mfma_f32_16x16x32_bf16(A1[t][ks], B1[ks], acc1[t], 0, 0, 0);
        }

        #pragma unroll
        for (int t = 0; t < 4; ++t) {
            const float r0 = fmaxf(acc1[t][0], 0.f), r1 = fmaxf(acc1[t][1], 0.f);
            const float r2 = fmaxf(acc1[t][2], 0.f), r3 = fmaxf(acc1[t][3], 0.f);
            tb[e * 32 + ((8 * t + 2 * g + 0) ^ sw)] = pk2(r0, r1);
            tb[e * 32 + ((8 * t + 2 * g + 1) ^ sw)] = pk2(r2, r3);
        }
        bf16x8 B2[2];
        #pragma unroll
        for (int ks = 0; ks < 2; ++ks) {
            union { uint4 u; bf16x8 b; } cvt;
            cvt.u = *(const uint4*)&tb[e * 32 + ((16 * ks + 4 * g) ^ sw)];
            B2[ks] = cvt.b;
        }

        f32x4 acc2[4];
        #pragma unroll
        for (int t = 0; t < 4; ++t) {
            acc2[t] = b2r[t];
            #pragma unroll
            for (int ks = 0; ks < 2; ++ks)
                acc2[t] = __builtin_amdgcn_mfma_f32_16x16x32_bf16(A2[t][ks], B2[ks], acc2[t], 0, 0, 0);
        }

        float z[4][4];
        float s1 = 0.f, s2 = 0.f;
        #pragma unroll
        for (int t = 0; t < 4; ++t) {
            const float4 hres = *(const float4*)(h + (size_t)node * 64 + 16 * t + 4 * g);
            #pragma unroll
            for (int r = 0; r < 4; ++r) {
                z[t][r] = acc2[t][r] + hres[r];
                s1 += z[t][r];
                s2 = fmaf(z[t][r], z[t][r], s2);
            }
        }
        s1 += __shfl_xor(s1, 16); s1 += __shfl_xor(s1, 32);
        s2 += __shfl_xor(s2, 16); s2 += __shfl_xor(s2, 32);
        const float mu   = s1 * (1.0f / 64.0f);
        const float var  = s2 * (1.0f / 64.0f) - mu * mu;
        const float rstd = rsqrtf(var + LNEPS);

        #pragma unroll
        for (int t = 0; t < 4; ++t) {
            float4 o;
            #pragma unroll
            for (int r = 0; r < 4; ++r)
                o[r] = (z[t][r] - mu) * rstd * gr[t][r] + br[t][r];
            *(float4*)(out + (size_t)node * 64 + 16 * t + 4 * g) = o;
        }
    }
}

extern "C" void kernel_launch(void* const* d_in, const int* in_sizes, int n_in,
                              void* d_out, int out_size, void* d_ws, size_t ws_size,
                              hipStream_t stream)
{
    const float* h    = (const float*)d_in[0];
    const float* x    = (const float*)d_in[1];
    const int*   ei   = (const int*)d_in[2];
    const float* We1  = (const float*)d_in[3];
    const float* be1  = (const float*)d_in[4];
    const float* We2  = (const float*)d_in[5];
    const float* be2  = (const float*)d_in[6];
    const float* Winf = (const float*)d_in[7];
    const float* binf = (const float*)d_in[8];
    const float* Wn1  = (const float*)d_in[9];
    const float* bn1  = (const float*)d_in[10];
    const float* Wn2  = (const float*)d_in[11];
    const float* bn2  = (const float*)d_in[12];
    const float* lng  = (const float*)d_in[13];
    const float* lnb  = (const float*)d_in[14];
    float* out = (float*)d_out;

    const size_t mi_bytes = (size_t)NN * HDIM * sizeof(float);          // 25.6 MB
    const size_t p_bytes  = (size_t)NN * HDIM * sizeof(unsigned short); // 12.8 MB
    const size_t sp_bytes = (size_t)NE * sizeof(int2);                  // 12.8 MB
    const size_t c_bytes  = (size_t)NSB * sizeof(int);                  // ~50 KB

    // sedge (6.4 MB, packed u32) aliases mi's first bytes: dead before memset(mi)
    const size_t need_sorted = mi_bytes + 2 * p_bytes + sp_bytes + 3 * c_bytes;

    if (ws_size >= need_sorted) {
        char* ws = (char*)d_ws;
        float*          mi    = (float*)ws;              ws += mi_bytes;
        unsigned short* Pt    = (unsigned short*)ws;     ws += p_bytes;
        unsigned short* Pb    = (unsigned short*)ws;     ws += p_bytes;
        int2*           spair = (int2*)ws;               ws += sp_bytes;
        int*            cnt2  = (int*)ws;                ws += c_bytes;
        int*            off2  = (int*)ws;                ws += c_bytes;
        int*            cur2  = (int*)ws;
        unsigned*       sedge = (unsigned*)mi;           // aliased, dead before memset

        hipMemsetAsync(cnt2, 0, c_bytes, stream);
        hipMemcpyAsync(out + (size_t)NN * HDIM, x, (size_t)NN * 3 * sizeof(float),
                       hipMemcpyDeviceToDevice, stream);

        hist2_kernel<<<2048, 256, 0, stream>>>(ei, cnt2);
        scanM_kernel<<<1, 1024, 0, stream>>>(cnt2, off2, cur2);
        scatter2_kernel<<<2048, 256, 0, stream>>>(ei, cur2, sedge);
        sort2_kernel<<<NB, 256, 0, stream>>>(sedge, off2, spair);
        pre_kernel<<<512, 256, 0, stream>>>(h, We1, be1, Pt, Pb);
        hipMemsetAsync(mi, 0, mi_bytes, stream);         // after sort2: frees sedge alias
        edge_kernel_sorted<<<2048, 256, 0, stream>>>(Pt, Pb, x, spair, We2, be2, Winf, binf, mi);
        node_kernel<<<512, 256, 0, stream>>>(h, mi, Wn1, bn1, Wn2, bn2, lng, lnb, out);
    } else {
        float* mi;
        unsigned short* Pt;
        unsigned short* Pb;
        if (ws_size >= mi_bytes + 2 * p_bytes) {
            mi = (float*)d_ws;
            Pt = (unsigned short*)((char*)d_ws + mi_bytes);
            Pb = (unsigned short*)((char*)d_ws + mi_bytes + p_bytes);
        } else {
            mi = out;
            Pt = (unsigned short*)d_ws;
            Pb = (unsigned short*)((char*)d_ws + p_bytes);
        }

        hipMemsetAsync(mi, 0, mi_bytes, stream);
        hipMemcpyAsync(out + (size_t)NN * HDIM, x, (size_t)NN * 3 * sizeof(float),
                       hipMemcpyDeviceToDevice, stream);

        pre_kernel<<<512, 256, 0, stream>>>(h, We1, be1, Pt, Pb);
        edge_kernel_unsorted<<<2048, 256, 0, stream>>>(Pt, Pb, x, ei, We2, be2, Winf, binf, mi);
        node_kernel<<<512, 256, 0, stream>>>(h, mi, Wn1, bn1, Wn2, bn2, lng, lnb, out);
    }
}

// Round 9
// 324.607 us; speedup vs baseline: 1.0689x; 1.0689x over previous
//
#include <hip/hip_runtime.h>
#include <hip/hip_bf16.h>
#include <math.h>

#define HDIM 64
#define NN   100000
#define NE   1600000
#define TEMP 30.0f
#define LNEPS 1e-5f

// bucketing: 64 nodes per bucket, 8 XCD shards
#define GSH  6
#define GSZ  64
#define NB   1563          // ceil(NN/64)
#define NSH  8
#define NSB  (NSH * NB)    // 12504 counters (bucket-major, shard-minor)
#define E2   782           // edges per hist/scatter block (2048 blocks)
#define SCANB 13           // ceil(NSB/1024)

typedef __attribute__((ext_vector_type(8))) short bf16x8;
typedef __attribute__((ext_vector_type(4))) float f32x4;

__device__ __forceinline__ short f2bf(float f) {
    __hip_bfloat16 b = __float2bfloat16(f);
    short s; __builtin_memcpy(&s, &b, 2); return s;
}
// packed 2xf32 -> 2xbf16 (RNE), single HW instruction on gfx950
__device__ __forceinline__ unsigned pk2(float lo, float hi) {
    unsigned r;
    asm("v_cvt_pk_bf16_f32 %0, %1, %2" : "=v"(r) : "v"(lo), "v"(hi));
    return r;
}
__device__ __forceinline__ float bf2f_lo(unsigned u) {
    union { unsigned u; float f; } c; c.u = u << 16; return c.f;
}
__device__ __forceinline__ float bf2f_hi(unsigned u) {
    union { unsigned u; float f; } c; c.u = u & 0xffff0000u; return c.f;
}
__device__ __forceinline__ float sigmoidf_(float z) { return 1.0f / (1.0f + __expf(-z)); }

// ============ Pre kernel: per-NODE factorization of edge GEMM1 ============
// Pt[n] = h[n] @ We1_top + be1 ; Pb[n] = h[n] @ We1_bot   (bf16 rows, 128 B)
extern "C" __global__ void __launch_bounds__(256, 2)
pre_kernel(const float* __restrict__ h,
           const float* __restrict__ We1, const float* __restrict__ be1,
           unsigned short* __restrict__ Pt, unsigned short* __restrict__ Pb)
{
    __shared__ float fx[4][1024];
    const int tid  = threadIdx.x;
    const int wib  = tid >> 6;
    const int lane = tid & 63;
    const int e = lane & 15, g = lane >> 4;
    float* fb = &fx[wib][0];
    const int se = ((e & 1) << 4) | ((e >> 1) & 3);

    bf16x8 At[4][2], Ab[4][2];
    f32x4 b1r[4];
    #pragma unroll
    for (int t = 0; t < 4; ++t) {
        #pragma unroll
        for (int ks = 0; ks < 2; ++ks) {
            bf16x8 a, b;
            #pragma unroll
            for (int j = 0; j < 8; ++j) {
                a[j] = f2bf(We1[(32 * ks + 8 * g + j) * 64 + 16 * t + e]);
                b[j] = f2bf(We1[(64 + 32 * ks + 8 * g + j) * 64 + 16 * t + e]);
            }
            At[t][ks] = a; Ab[t][ks] = b;
        }
        #pragma unroll
        for (int r = 0; r < 4; ++r) b1r[t][r] = be1[16 * t + 4 * g + r];
    }

    const int gwid = blockIdx.x * 4 + wib;
    const int nw   = gridDim.x * 4;

    for (int tile = gwid; tile < NN / 16; tile += nw) {
        const int node = tile * 16 + e;

        bf16x8 B[2];
        #pragma unroll
        for (int ks = 0; ks < 2; ++ks) {
            const float4* p = (const float4*)(h + (size_t)node * 64 + ks * 32 + 8 * g);
            const float4 f0 = p[0], f1 = p[1];
            union { uint4 u; bf16x8 b; } cvt;
            cvt.u.x = pk2(f0.x, f0.y); cvt.u.y = pk2(f0.z, f0.w);
            cvt.u.z = pk2(f1.x, f1.y); cvt.u.w = pk2(f1.z, f1.w);
            B[ks] = cvt.b;
        }

        f32x4 aT[4], aB[4];
        #pragma unroll
        for (int t = 0; t < 4; ++t) {
            aT[t] = b1r[t];
            aB[t] = (f32x4){0.f, 0.f, 0.f, 0.f};
            #pragma unroll
            for (int ks = 0; ks < 2; ++ks) {
                aT[t] = __builtin_amdgcn_mfma_f32_16x16x32_bf16(At[t][ks], B[ks], aT[t], 0, 0, 0);
                aB[t] = __builtin_amdgcn_mfma_f32_16x16x32_bf16(Ab[t][ks], B[ks], aB[t], 0, 0, 0);
            }
        }

        #pragma unroll
        for (int t = 0; t < 4; ++t)
            #pragma unroll
            for (int r = 0; r < 4; ++r)
                fb[e * 64 + ((16 * t + 4 * g + r) ^ se)] = aT[t][r];
        #pragma unroll
        for (int q = 0; q < 2; ++q) {
            const int row = q * 8 + (lane >> 3);
            const int sr  = ((row & 1) << 4) | ((row >> 1) & 3);
            const int c0  = (lane & 7) * 8;
            uint4 o;
            o.x = pk2(fb[row * 64 + ((c0 + 0) ^ sr)], fb[row * 64 + ((c0 + 1) ^ sr)]);
            o.y = pk2(fb[row * 64 + ((c0 + 2) ^ sr)], fb[row * 64 + ((c0 + 3) ^ sr)]);
            o.z = pk2(fb[row * 64 + ((c0 + 4) ^ sr)], fb[row * 64 + ((c0 + 5) ^ sr)]);
            o.w = pk2(fb[row * 64 + ((c0 + 6) ^ sr)], fb[row * 64 + ((c0 + 7) ^ sr)]);
            *(uint4*)((char*)Pt + (size_t)tile * 2048 + q * 1024 + lane * 16) = o;
        }

        #pragma unroll
        for (int t = 0; t < 4; ++t)
            #pragma unroll
            for (int r = 0; r < 4; ++r)
                fb[e * 64 + ((16 * t + 4 * g + r) ^ se)] = aB[t][r];
        #pragma unroll
        for (int q = 0; q < 2; ++q) {
            const int row = q * 8 + (lane >> 3);
            const int sr  = ((row & 1) << 4) | ((row >> 1) & 3);
            const int c0  = (lane & 7) * 8;
            uint4 o;
            o.x = pk2(fb[row * 64 + ((c0 + 0) ^ sr)], fb[row * 64 + ((c0 + 1) ^ sr)]);
            o.y = pk2(fb[row * 64 + ((c0 + 2) ^ sr)], fb[row * 64 + ((c0 + 3) ^ sr)]);
            o.z = pk2(fb[row * 64 + ((c0 + 4) ^ sr)], fb[row * 64 + ((c0 + 5) ^ sr)]);
            o.w = pk2(fb[row * 64 + ((c0 + 6) ^ sr)], fb[row * 64 + ((c0 + 7) ^ sr)]);
            *(uint4*)((char*)Pb + (size_t)tile * 2048 + q * 1024 + lane * 16) = o;
        }
    }
}

// ============ Bucket sort: sharded hist / scan / scatter ============
extern "C" __global__ void __launch_bounds__(256)
hist2_kernel(const int* __restrict__ ei, int* __restrict__ cnt2)
{
    const int b  = blockIdx.x;                   // grid must be 2048
    const int i0 = b * E2;
    const int i1 = (i0 + E2 < NE) ? i0 + E2 : NE;
    const int sh = b & (NSH - 1);
    for (int i = i0 + threadIdx.x; i < i1; i += 256)
        atomicAdd(&cnt2[(ei[NE + i] >> GSH) * NSH + sh], 1);
}

extern "C" __global__ void __launch_bounds__(1024)
scanA_kernel(const int* __restrict__ cnt2, int* __restrict__ off2, int* __restrict__ bsum)
{
    __shared__ int sh[1024];
    const int t = threadIdx.x;
    const int i = blockIdx.x * 1024 + t;
    const int v = (i < NSB) ? cnt2[i] : 0;
    sh[t] = v;
    __syncthreads();
    for (int off = 1; off < 1024; off <<= 1) {
        const int u = (t >= off) ? sh[t - off] : 0;
        __syncthreads();
        sh[t] += u;
        __syncthreads();
    }
    if (i < NSB) off2[i] = sh[t] - v;
    if (t == 1023) bsum[blockIdx.x] = sh[1023];
}

extern "C" __global__ void __launch_bounds__(64)
scanB_kernel(int* __restrict__ bsum)
{
    if (threadIdx.x == 0) {
        int run = 0;
        for (int j = 0; j < SCANB; ++j) { const int v = bsum[j]; bsum[j] = run; run += v; }
    }
}

extern "C" __global__ void __launch_bounds__(1024)
scanC_kernel(int* __restrict__ off2, const int* __restrict__ bsum, int* __restrict__ cur2)
{
    const int i = blockIdx.x * 1024 + threadIdx.x;
    if (i < NSB) {
        const int o = off2[i] + bsum[blockIdx.x];
        off2[i] = o;
        cur2[i] = o;
    }
}

extern "C" __global__ void __launch_bounds__(256)
scatter2_kernel(const int* __restrict__ ei, int* __restrict__ cur2,
                unsigned* __restrict__ sedge)
{
    const int b  = blockIdx.x;                   // grid must be 2048
    const int i0 = b * E2;
    const int i1 = (i0 + E2 < NE) ? i0 + E2 : NE;
    const int sh = b & (NSH - 1);
    for (int i = i0 + threadIdx.x; i < i1; i += 256) {
        const int s = ei[i];
        const int d = ei[NE + i];
        const int pos = atomicAdd(&cur2[(d >> GSH) * NSH + sh], 1);
        sedge[pos] = (unsigned)s | ((unsigned)(d & (GSZ - 1)) << 17);
    }
}

// ============ Bucket sort stage 2: per-bucket exact refinement ============
extern "C" __global__ void __launch_bounds__(256)
sort2_kernel(const unsigned* __restrict__ sedge, const int* __restrict__ off2,
             int2* __restrict__ spair)
{
    __shared__ int hist[GSZ], base[GSZ], curs[GSZ];
    const int tid = threadIdx.x;
    const int b   = blockIdx.x;
    const int r0  = off2[b * NSH];
    const int r1  = (b == NB - 1) ? NE : off2[(b + 1) * NSH];

    if (tid < GSZ) hist[tid] = 0;
    __syncthreads();
    for (int i = r0 + tid; i < r1; i += 256)
        atomicAdd(&hist[(sedge[i] >> 17) & (GSZ - 1)], 1);
    __syncthreads();
    if (tid == 0) {
        int run = 0;
        for (int j = 0; j < GSZ; ++j) { base[j] = run; run += hist[j]; }
    }
    __syncthreads();
    if (tid < GSZ) curs[tid] = base[tid];
    __syncthreads();
    for (int i = r0 + tid; i < r1; i += 256) {
        const unsigned pk = sedge[i];
        const int dl = (pk >> 17) & (GSZ - 1);
        const int pos = r0 + atomicAdd(&curs[dl], 1);
        spair[pos] = make_int2((int)(pk & 0x1FFFFu), (b << GSH) | dl);
    }
}

// ============ Edge kernel (sorted): R4-proven register-run accumulation ====
extern "C" __global__ void __launch_bounds__(256, 2)
edge_kernel_sorted(const unsigned short* __restrict__ Pt, const unsigned short* __restrict__ Pb,
                   const float* __restrict__ x, const int2* __restrict__ spair,
                   const float* __restrict__ We2, const float* __restrict__ be2,
                   const float* __restrict__ Winf, const float* __restrict__ binf,
                   float* __restrict__ mi)
{
    __shared__ float fx[4][1024];
    const int tid  = threadIdx.x;
    const int wib  = tid >> 6;
    const int lane = tid & 63;
    const int e = lane & 15, g = lane >> 4;
    float* fb = &fx[wib][0];
    const int se = ((e & 1) << 4) | ((e >> 1) & 3);

    bf16x8 A2[4][2];
    f32x4 b2r[4], wir[4];
    #pragma unroll
    for (int t = 0; t < 4; ++t) {
        #pragma unroll
        for (int ks = 0; ks < 2; ++ks) {
            bf16x8 a;
            #pragma unroll
            for (int j = 0; j < 8; ++j)
                a[j] = f2bf(We2[(32 * ks + 8 * g + j) * 64 + 16 * t + e]);
            A2[t][ks] = a;
        }
        #pragma unroll
        for (int r = 0; r < 4; ++r) {
            b2r[t][r] = be2[16 * t + 4 * g + r];
            wir[t][r] = Winf[16 * t + 4 * g + r];
        }
    }
    const float binf0 = binf[0];

    const int NT     = NE / 16;
    const int nwaves = gridDim.x * 4;
    const int gwid   = blockIdx.x * 4 + wib;
    const int chunk  = (NT + nwaves - 1) / nwaves;
    const int t0 = gwid * chunk;
    const int t1 = (t0 + chunk < NT) ? t0 + chunk : NT;

    float racc  = 0.f;   // running row accumulator, channel = lane
    int   rrow  = -1;    // wave-uniform current node id

    for (int tile = t0; tile < t1; ++tile) {
        const int eid = tile * 16 + e;
        const int2 sd = spair[eid];
        const int sN = sd.x;
        const int dN = sd.y;

        const float dx = x[dN * 3 + 0] - x[sN * 3 + 0];
        const float dy = x[dN * 3 + 1] - x[sN * 3 + 1];
        const float dz = x[dN * 3 + 2] - x[sN * 3 + 2];
        const float dsq = dx * dx + dy * dy + dz * dz;
        const float edis = sigmoidf_(TEMP / (sqrtf(dsq) + 1e-8f));

        // B2 frags: relu(Pt[dst] + Pb[src]) -> packed bf16 via v_cvt_pk_bf16_f32
        bf16x8 B2[2];
        #pragma unroll
        for (int ks = 0; ks < 2; ++ks) {
            const uint4 ut = *(const uint4*)(Pt + (size_t)dN * 64 + 32 * ks + 8 * g);
            const uint4 ub = *(const uint4*)(Pb + (size_t)sN * 64 + 32 * ks + 8 * g);
            const float v0 = fmaxf(bf2f_lo(ut.x) + bf2f_lo(ub.x), 0.f);
            const float v1 = fmaxf(bf2f_hi(ut.x) + bf2f_hi(ub.x), 0.f);
            const float v2 = fmaxf(bf2f_lo(ut.y) + bf2f_lo(ub.y), 0.f);
            const float v3 = fmaxf(bf2f_hi(ut.y) + bf2f_hi(ub.y), 0.f);
            const float v4 = fmaxf(bf2f_lo(ut.z) + bf2f_lo(ub.z), 0.f);
            const float v5 = fmaxf(bf2f_hi(ut.z) + bf2f_hi(ub.z), 0.f);
            const float v6 = fmaxf(bf2f_lo(ut.w) + bf2f_lo(ub.w), 0.f);
            const float v7 = fmaxf(bf2f_hi(ut.w) + bf2f_hi(ub.w), 0.f);
            union { uint4 u; bf16x8 b; } cvt;
            cvt.u.x = pk2(v0, v1); cvt.u.y = pk2(v2, v3);
            cvt.u.z = pk2(v4, v5); cvt.u.w = pk2(v6, v7);
            B2[ks] = cvt.b;
        }

        f32x4 acc2[4];
        #pragma unroll
        for (int t = 0; t < 4; ++t) {
            acc2[t] = b2r[t];
            #pragma unroll
            for (int ks = 0; ks < 2; ++ks)
                acc2[t] = __builtin_amdgcn_mfma_f32_16x16x32_bf16(A2[t][ks], B2[ks], acc2[t], 0, 0, 0);
        }

        float m[4][4];
        float p = 0.f;
        #pragma unroll
        for (int t = 0; t < 4; ++t)
            #pragma unroll
            for (int r = 0; r < 4; ++r) {
                m[t][r] = fmaxf(acc2[t][r], 0.f);
                p = fmaf(m[t][r], wir[t][r], p);
            }
        p += __shfl_xor(p, 16);
        p += __shfl_xor(p, 32);
        const float w = sigmoidf_((p + binf0) * edis);

        #pragma unroll
        for (int t = 0; t < 4; ++t)
            #pragma unroll
            for (int r = 0; r < 4; ++r)
                fb[e * 64 + ((16 * t + 4 * g + r) ^ se)] = m[t][r] * w;

        #pragma unroll
        for (int i = 0; i < 16; ++i) {
            const int row = __builtin_amdgcn_readlane(dN, i);
            const int si = ((i & 1) << 4) | ((i >> 1) & 3);
            const float v = fb[i * 64 + (lane ^ si)];
            if (row != rrow) {
                if (rrow >= 0) atomicAdd(mi + (size_t)rrow * 64 + lane, racc);
                rrow = row; racc = v;
            } else {
                racc += v;
            }
        }
    }
    if (rrow >= 0) atomicAdd(mi + (size_t)rrow * 64 + lane, racc);
}

// ============ Edge kernel (unsorted fallback, small-ws path) ============
extern "C" __global__ void __launch_bounds__(256, 2)
edge_kernel_unsorted(const unsigned short* __restrict__ Pt, const unsigned short* __restrict__ Pb,
                     const float* __restrict__ x, const int* __restrict__ ei,
                     const float* __restrict__ We2, const float* __restrict__ be2,
                     const float* __restrict__ Winf, const float* __restrict__ binf,
                     float* __restrict__ mi)
{
    __shared__ float fx[4][1024];
    const int tid  = threadIdx.x;
    const int wib  = tid >> 6;
    const int lane = tid & 63;
    const int e = lane & 15, g = lane >> 4;
    float* fb = &fx[wib][0];
    const int se = ((e & 1) << 4) | ((e >> 1) & 3);

    bf16x8 A2[4][2];
    f32x4 b2r[4], wir[4];
    #pragma unroll
    for (int t = 0; t < 4; ++t) {
        #pragma unroll
        for (int ks = 0; ks < 2; ++ks) {
            bf16x8 a;
            #pragma unroll
            for (int j = 0; j < 8; ++j)
                a[j] = f2bf(We2[(32 * ks + 8 * g + j) * 64 + 16 * t + e]);
            A2[t][ks] = a;
        }
        #pragma unroll
        for (int r = 0; r < 4; ++r) {
            b2r[t][r] = be2[16 * t + 4 * g + r];
            wir[t][r] = Winf[16 * t + 4 * g + r];
        }
    }
    const float binf0 = binf[0];

    const int gwid = blockIdx.x * 4 + wib;
    const int nw   = gridDim.x * 4;

    for (int tile = gwid; tile < NE / 16; tile += nw) {
        const int eid = tile * 16 + e;
        const int sN = ei[eid];
        const int dN = ei[NE + eid];

        const float dx = x[dN * 3 + 0] - x[sN * 3 + 0];
        const float dy = x[dN * 3 + 1] - x[sN * 3 + 1];
        const float dz = x[dN * 3 + 2] - x[sN * 3 + 2];
        const float dsq = dx * dx + dy * dy + dz * dz;
        const float edis = sigmoidf_(TEMP / (sqrtf(dsq) + 1e-8f));

        bf16x8 B2[2];
        #pragma unroll
        for (int ks = 0; ks < 2; ++ks) {
            const uint4 ut = *(const uint4*)(Pt + (size_t)dN * 64 + 32 * ks + 8 * g);
            const uint4 ub = *(const uint4*)(Pb + (size_t)sN * 64 + 32 * ks + 8 * g);
            const float v0 = fmaxf(bf2f_lo(ut.x) + bf2f_lo(ub.x), 0.f);
            const float v1 = fmaxf(bf2f_hi(ut.x) + bf2f_hi(ub.x), 0.f);
            const float v2 = fmaxf(bf2f_lo(ut.y) + bf2f_lo(ub.y), 0.f);
            const float v3 = fmaxf(bf2f_hi(ut.y) + bf2f_hi(ub.y), 0.f);
            const float v4 = fmaxf(bf2f_lo(ut.z) + bf2f_lo(ub.z), 0.f);
            const float v5 = fmaxf(bf2f_hi(ut.z) + bf2f_hi(ub.z), 0.f);
            const float v6 = fmaxf(bf2f_lo(ut.w) + bf2f_lo(ub.w), 0.f);
            const float v7 = fmaxf(bf2f_hi(ut.w) + bf2f_hi(ub.w), 0.f);
            union { uint4 u; bf16x8 b; } cvt;
            cvt.u.x = pk2(v0, v1); cvt.u.y = pk2(v2, v3);
            cvt.u.z = pk2(v4, v5); cvt.u.w = pk2(v6, v7);
            B2[ks] = cvt.b;
        }

        f32x4 acc2[4];
        #pragma unroll
        for (int t = 0; t < 4; ++t) {
            acc2[t] = b2r[t];
            #pragma unroll
            for (int ks = 0; ks < 2; ++ks)
                acc2[t] = __builtin_amdgcn_mfma_f32_16x16x32_bf16(A2[t][ks], B2[ks], acc2[t], 0, 0, 0);
        }

        float m[4][4];
        float p = 0.f;
        #pragma unroll
        for (int t = 0; t < 4; ++t)
            #pragma unroll
            for (int r = 0; r < 4; ++r) {
                m[t][r] = fmaxf(acc2[t][r], 0.f);
                p = fmaf(m[t][r], wir[t][r], p);
            }
        p += __shfl_xor(p, 16);
        p += __shfl_xor(p, 32);
        const float w = sigmoidf_((p + binf0) * edis);

        #pragma unroll
        for (int t = 0; t < 4; ++t)
            #pragma unroll
            for (int r = 0; r < 4; ++r)
                fb[e * 64 + ((16 * t + 4 * g + r) ^ se)] = m[t][r] * w;

        #pragma unroll
        for (int i = 0; i < 16; ++i) {
            const int row = __shfl(dN, i);
            const int si = ((i & 1) << 4) | ((i >> 1) & 3);
            const float v = fb[i * 64 + (lane ^ si)];
            atomicAdd(mi + (size_t)row * 64 + lane, v);
        }
    }
}

// ============ Node kernel: same B2B MFMA + residual + LayerNorm =============
extern "C" __global__ void __launch_bounds__(256, 2)
node_kernel(const float* __restrict__ h, const float* __restrict__ mi_,
            const float* __restrict__ Wn1, const float* __restrict__ bn1,
            const float* __restrict__ Wn2, const float* __restrict__ bn2,
            const float* __restrict__ lng, const float* __restrict__ lnb,
            float* __restrict__ out)
{
    __shared__ unsigned xlds[4][16 * 32];
    const int tid  = threadIdx.x;
    const int wib  = tid >> 6;
    const int lane = tid & 63;
    const int e = lane & 15, g = lane >> 4;
    unsigned* tb = &xlds[wib][0];
    const int sw = (e & 7) << 2;

    bf16x8 A1[4][4], A2[4][2];
    f32x4 b1r[4], b2r[4], gr[4], br[4];
    #pragma unroll
    for (int t = 0; t < 4; ++t) {
        #pragma unroll
        for (int ks = 0; ks < 4; ++ks) {
            bf16x8 a;
            #pragma unroll
            for (int j = 0; j < 8; ++j)
                a[j] = f2bf(Wn1[(32 * ks + 8 * g + j) * 64 + 16 * t + e]);
            A1[t][ks] = a;
        }
        #pragma unroll
        for (int ks = 0; ks < 2; ++ks) {
            bf16x8 a;
            #pragma unroll
            for (int j = 0; j < 8; ++j)
                a[j] = f2bf(Wn2[(32 * ks + 8 * g + j) * 64 + 16 * t + e]);
            A2[t][ks] = a;
        }
        #pragma unroll
        for (int r = 0; r < 4; ++r) {
            b1r[t][r] = bn1[16 * t + 4 * g + r];
            b2r[t][r] = bn2[16 * t + 4 * g + r];
            gr[t][r]  = lng[16 * t + 4 * g + r];
            br[t][r]  = lnb[16 * t + 4 * g + r];
        }
    }

    const int gwid = blockIdx.x * 4 + wib;
    const int nw   = gridDim.x * 4;

    for (int tile = gwid; tile < NN / 16; tile += nw) {
        const int node = tile * 16 + e;

        bf16x8 B1[4];
        #pragma unroll
        for (int ks = 0; ks < 4; ++ks) {
            const float* srcp = (ks < 2) ? mi_ : h;
            const float4* p = (const float4*)(srcp + (size_t)node * 64 + (ks & 1) * 32 + 8 * g);
            const float4 f0 = p[0], f1 = p[1];
            union { uint4 u; bf16x8 b; } cvt;
            cvt.u.x = pk2(f0.x, f0.y); cvt.u.y = pk2(f0.z, f0.w);
            cvt.u.z = pk2(f1.x, f1.y); cvt.u.w = pk2(f1.z, f1.w);
            B1[ks] = cvt.b;
        }

        f32x4 acc1[4];
        #pragma unroll
        for (int t = 0; t < 4; ++t) {
            acc1[t] = b1r[t];
            #pragma unroll
            for (int ks = 0; ks < 4; ++ks)
                acc1[t] = __builtin_amdgcn_mfma_f32_16x16x32_bf16(A1[t][ks], B1[ks], acc1[t], 0, 0, 0);
        }

        #pragma unroll
        for (int t = 0; t < 4; ++t) {
            const float r0 = fmaxf(acc1[t][0], 0.f), r1 = fmaxf(acc1[t][1], 0.f);
            const float r2 = fmaxf(acc1[t][2], 0.f), r3 = fmaxf(acc1[t][3], 0.f);
            tb[e * 32 + ((8 * t + 2 * g + 0) ^ sw)] = pk2(r0, r1);
            tb[e * 32 + ((8 * t + 2 * g + 1) ^ sw)] = pk2(r2, r3);
        }
        bf16x8 B2[2];
        #pragma unroll
        for (int ks = 0; ks < 2; ++ks) {
            union { uint4 u; bf16x8 b; } cvt;
            cvt.u = *(const uint4*)&tb[e * 32 + ((16 * ks + 4 * g) ^ sw)];
            B2[ks] = cvt.b;
        }

        f32x4 acc2[4];
        #pragma unroll
        for (int t = 0; t < 4; ++t) {
            acc2[t] = b2r[t];
            #pragma unroll
            for (int ks = 0; ks < 2; ++ks)
                acc2[t] = __builtin_amdgcn_mfma_f32_16x16x32_bf16(A2[t][ks], B2[ks], acc2[t], 0, 0, 0);
        }

        float z[4][4];
        float s1 = 0.f, s2 = 0.f;
        #pragma unroll
        for (int t = 0; t < 4; ++t) {
            const float4 hres = *(const float4*)(h + (size_t)node * 64 + 16 * t + 4 * g);
            #pragma unroll
            for (int r = 0; r < 4; ++r) {
                z[t][r] = acc2[t][r] + hres[r];
                s1 += z[t][r];
                s2 = fmaf(z[t][r], z[t][r], s2);
            }
        }
        s1 += __shfl_xor(s1, 16); s1 += __shfl_xor(s1, 32);
        s2 += __shfl_xor(s2, 16); s2 += __shfl_xor(s2, 32);
        const float mu   = s1 * (1.0f / 64.0f);
        const float var  = s2 * (1.0f / 64.0f) - mu * mu;
        const float rstd = rsqrtf(var + LNEPS);

        #pragma unroll
        for (int t = 0; t < 4; ++t) {
            float4 o;
            #pragma unroll
            for (int r = 0; r < 4; ++r)
                o[r] = (z[t][r] - mu) * rstd * gr[t][r] + br[t][r];
            *(float4*)(out + (size_t)node * 64 + 16 * t + 4 * g) = o;
        }
    }
}

extern "C" void kernel_launch(void* const* d_in, const int* in_sizes, int n_in,
                              void* d_out, int out_size, void* d_ws, size_t ws_size,
                              hipStream_t stream)
{
    const float* h    = (const float*)d_in[0];
    const float* x    = (const float*)d_in[1];
    const int*   ei   = (const int*)d_in[2];
    const float* We1  = (const float*)d_in[3];
    const float* be1  = (const float*)d_in[4];
    const float* We2  = (const float*)d_in[5];
    const float* be2  = (const float*)d_in[6];
    const float* Winf = (const float*)d_in[7];
    const float* binf = (const float*)d_in[8];
    const float* Wn1  = (const float*)d_in[9];
    const float* bn1  = (const float*)d_in[10];
    const float* Wn2  = (const float*)d_in[11];
    const float* bn2  = (const float*)d_in[12];
    const float* lng  = (const float*)d_in[13];
    const float* lnb  = (const float*)d_in[14];
    float* out = (float*)d_out;

    const size_t mi_bytes = (size_t)NN * HDIM * sizeof(float);          // 25.6 MB
    const size_t p_bytes  = (size_t)NN * HDIM * sizeof(unsigned short); // 12.8 MB
    const size_t sp_bytes = (size_t)NE * sizeof(int2);                  // 12.8 MB
    const size_t c_bytes  = (size_t)NSB * sizeof(int);                  // ~50 KB
    const size_t bs_bytes = SCANB * sizeof(int);

    // sedge (6.4 MB, packed u32) aliases mi's first bytes: dead before memset(mi)
    const size_t need_sorted = mi_bytes + 2 * p_bytes + sp_bytes + 3 * c_bytes + bs_bytes;

    if (ws_size >= need_sorted) {
        char* ws = (char*)d_ws;
        float*          mi    = (float*)ws;              ws += mi_bytes;
        unsigned short* Pt    = (unsigned short*)ws;     ws += p_bytes;
        unsigned short* Pb    = (unsigned short*)ws;     ws += p_bytes;
        int2*           spair = (int2*)ws;               ws += sp_bytes;
        int*            cnt2  = (int*)ws;                ws += c_bytes;
        int*            off2  = (int*)ws;                ws += c_bytes;
        int*            cur2  = (int*)ws;                ws += c_bytes;
        int*            bsum  = (int*)ws;
        unsigned*       sedge = (unsigned*)mi;           // aliased, dead before memset

        hipMemsetAsync(cnt2, 0, c_bytes, stream);
        hipMemcpyAsync(out + (size_t)NN * HDIM, x, (size_t)NN * 3 * sizeof(float),
                       hipMemcpyDeviceToDevice, stream);

        hist2_kernel<<<2048, 256, 0, stream>>>(ei, cnt2);
        scanA_kernel<<<SCANB, 1024, 0, stream>>>(cnt2, off2, bsum);
        scanB_kernel<<<1, 64, 0, stream>>>(bsum);
        scanC_kernel<<<SCANB, 1024, 0, stream>>>(off2, bsum, cur2);
        scatter2_kernel<<<2048, 256, 0, stream>>>(ei, cur2, sedge);
        sort2_kernel<<<NB, 256, 0, stream>>>(sedge, off2, spair);
        pre_kernel<<<512, 256, 0, stream>>>(h, We1, be1, Pt, Pb);
        hipMemsetAsync(mi, 0, mi_bytes, stream);         // after sort2: frees sedge alias
        edge_kernel_sorted<<<2048, 256, 0, stream>>>(Pt, Pb, x, spair, We2, be2, Winf, binf, mi);
        node_kernel<<<512, 256, 0, stream>>>(h, mi, Wn1, bn1, Wn2, bn2, lng, lnb, out);
    } else {
        float* mi;
        unsigned short* Pt;
        unsigned short* Pb;
        if (ws_size >= mi_bytes + 2 * p_bytes) {
            mi = (float*)d_ws;
            Pt = (unsigned short*)((char*)d_ws + mi_bytes);
            Pb = (unsigned short*)((char*)d_ws + mi_bytes + p_bytes);
        } else {
            mi = out;
            Pt = (unsigned short*)d_ws;
            Pb = (unsigned short*)((char*)d_ws + p_bytes);
        }

        hipMemsetAsync(mi, 0, mi_bytes, stream);
        hipMemcpyAsync(out + (size_t)NN * HDIM, x, (size_t)NN * 3 * sizeof(float),
                       hipMemcpyDeviceToDevice, stream);

        pre_kernel<<<512, 256, 0, stream>>>(h, We1, be1, Pt, Pb);
        edge_kernel_unsorted<<<2048, 256, 0, stream>>>(Pt, Pb, x, ei, We2, be2, Winf, binf, mi);
        node_kernel<<<512, 256, 0, stream>>>(h, mi, Wn1, bn1, Wn2, bn2, lng, lnb, out);
    }
}

// Round 10
// 220.568 us; speedup vs baseline: 1.5731x; 1.4717x over previous
//
#include <hip/hip_runtime.h>
#include <hip/hip_bf16.h>
#include <math.h>

#define HDIM 64
#define NN   100000
#define NE   1600000
#define TEMP 30.0f
#define LNEPS 1e-5f

// bucketing: 64 nodes per bucket; privatized sort over 64 exclusive edge ranges
#define GSH   6
#define GSZ   64
#define NB    1563           // ceil(NN/64) buckets
#define NBLK  64             // privatized hist/scatter blocks (exclusive ranges)
#define EPB   (NE / NBLK)    // 25000 edges per block
#define NCNT  (NB * NBLK)    // 100032 per-(bucket,block) counters
#define SCANB2 98            // ceil(NCNT/1024)

typedef __attribute__((ext_vector_type(8))) short bf16x8;
typedef __attribute__((ext_vector_type(4))) float f32x4;

__device__ __forceinline__ short f2bf(float f) {
    __hip_bfloat16 b = __float2bfloat16(f);
    short s; __builtin_memcpy(&s, &b, 2); return s;
}
__device__ __forceinline__ unsigned pk2(float lo, float hi) {
    return (unsigned)(unsigned short)f2bf(lo) | ((unsigned)(unsigned short)f2bf(hi) << 16);
}
__device__ __forceinline__ float bf2f(unsigned u) {
    union { unsigned u; float f; } c; c.u = u << 16; return c.f;
}
__device__ __forceinline__ float sigmoidf_(float z) { return 1.0f / (1.0f + __expf(-z)); }

// ============ Front kernel: privatized hist (64 blocks) || pre (512 blocks) ====
// hist role: LDS histogram of its exclusive 25K-edge range -> non-atomic store
// to cnt3[k*64+b]. pre role: Pt[n]=h@We1_top+be1, Pb[n]=h@We1_bot (bf16 rows).
extern "C" __global__ void __launch_bounds__(256, 2)
front_kernel(const float* __restrict__ h,
             const float* __restrict__ We1, const float* __restrict__ be1,
             unsigned short* __restrict__ Pt, unsigned short* __restrict__ Pb,
             const int* __restrict__ ei, int* __restrict__ cnt3)
{
    __shared__ float fx[4][1024];    // 16 KB: pre transpose buffers / hist bins
    const int b = blockIdx.x;

    if (b < NBLK) {
        // ---- hist role: zero global atomics ----
        int* hbin = (int*)&fx[0][0];           // 1563 ints (6.25 KB)
        const int tid = threadIdx.x;
        for (int k = tid; k < NB; k += 256) hbin[k] = 0;
        __syncthreads();
        const int i0 = b * EPB;
        for (int i = i0 + tid; i < i0 + EPB; i += 256)
            atomicAdd(&hbin[ei[NE + i] >> GSH], 1);
        __syncthreads();
        for (int k = tid; k < NB; k += 256)
            cnt3[k * NBLK + b] = hbin[k];      // exclusive slot: plain store
        return;
    }

    // ---- pre role ----
    const int pb   = b - NBLK;
    const int tid  = threadIdx.x;
    const int wib  = tid >> 6;
    const int lane = tid & 63;
    const int e = lane & 15, g = lane >> 4;
    float* fb = &fx[wib][0];
    const int se = ((e & 1) << 4) | ((e >> 1) & 3);

    bf16x8 At[4][2], Ab[4][2];
    f32x4 b1r[4];
    #pragma unroll
    for (int t = 0; t < 4; ++t) {
        #pragma unroll
        for (int ks = 0; ks < 2; ++ks) {
            bf16x8 a, bb;
            #pragma unroll
            for (int j = 0; j < 8; ++j) {
                a[j]  = f2bf(We1[(32 * ks + 8 * g + j) * 64 + 16 * t + e]);
                bb[j] = f2bf(We1[(64 + 32 * ks + 8 * g + j) * 64 + 16 * t + e]);
            }
            At[t][ks] = a; Ab[t][ks] = bb;
        }
        #pragma unroll
        for (int r = 0; r < 4; ++r) b1r[t][r] = be1[16 * t + 4 * g + r];
    }

    const int gwid = pb * 4 + wib;
    const int nw   = 512 * 4;

    for (int tile = gwid; tile < NN / 16; tile += nw) {
        const int node = tile * 16 + e;

        bf16x8 B[2];
        #pragma unroll
        for (int ks = 0; ks < 2; ++ks) {
            const float4* p = (const float4*)(h + (size_t)node * 64 + ks * 32 + 8 * g);
            const float4 f0 = p[0], f1 = p[1];
            bf16x8 bb;
            bb[0] = f2bf(f0.x); bb[1] = f2bf(f0.y); bb[2] = f2bf(f0.z); bb[3] = f2bf(f0.w);
            bb[4] = f2bf(f1.x); bb[5] = f2bf(f1.y); bb[6] = f2bf(f1.z); bb[7] = f2bf(f1.w);
            B[ks] = bb;
        }

        f32x4 aT[4], aB[4];
        #pragma unroll
        for (int t = 0; t < 4; ++t) {
            aT[t] = b1r[t];
            aB[t] = (f32x4){0.f, 0.f, 0.f, 0.f};
            #pragma unroll
            for (int ks = 0; ks < 2; ++ks) {
                aT[t] = __builtin_amdgcn_mfma_f32_16x16x32_bf16(At[t][ks], B[ks], aT[t], 0, 0, 0);
                aB[t] = __builtin_amdgcn_mfma_f32_16x16x32_bf16(Ab[t][ks], B[ks], aB[t], 0, 0, 0);
            }
        }

        #pragma unroll
        for (int t = 0; t < 4; ++t)
            #pragma unroll
            for (int r = 0; r < 4; ++r)
                fb[e * 64 + ((16 * t + 4 * g + r) ^ se)] = aT[t][r];
        #pragma unroll
        for (int q = 0; q < 2; ++q) {
            const int row = q * 8 + (lane >> 3);
            const int sr  = ((row & 1) << 4) | ((row >> 1) & 3);
            const int c0  = (lane & 7) * 8;
            uint4 o;
            o.x = pk2(fb[row * 64 + ((c0 + 0) ^ sr)], fb[row * 64 + ((c0 + 1) ^ sr)]);
            o.y = pk2(fb[row * 64 + ((c0 + 2) ^ sr)], fb[row * 64 + ((c0 + 3) ^ sr)]);
            o.z = pk2(fb[row * 64 + ((c0 + 4) ^ sr)], fb[row * 64 + ((c0 + 5) ^ sr)]);
            o.w = pk2(fb[row * 64 + ((c0 + 6) ^ sr)], fb[row * 64 + ((c0 + 7) ^ sr)]);
            *(uint4*)((char*)Pt + (size_t)tile * 2048 + q * 1024 + lane * 16) = o;
        }

        #pragma unroll
        for (int t = 0; t < 4; ++t)
            #pragma unroll
            for (int r = 0; r < 4; ++r)
                fb[e * 64 + ((16 * t + 4 * g + r) ^ se)] = aB[t][r];
        #pragma unroll
        for (int q = 0; q < 2; ++q) {
            const int row = q * 8 + (lane >> 3);
            const int sr  = ((row & 1) << 4) | ((row >> 1) & 3);
            const int c0  = (lane & 7) * 8;
            uint4 o;
            o.x = pk2(fb[row * 64 + ((c0 + 0) ^ sr)], fb[row * 64 + ((c0 + 1) ^ sr)]);
            o.y = pk2(fb[row * 64 + ((c0 + 2) ^ sr)], fb[row * 64 + ((c0 + 3) ^ sr)]);
            o.z = pk2(fb[row * 64 + ((c0 + 4) ^ sr)], fb[row * 64 + ((c0 + 5) ^ sr)]);
            o.w = pk2(fb[row * 64 + ((c0 + 6) ^ sr)], fb[row * 64 + ((c0 + 7) ^ sr)]);
            *(uint4*)((char*)Pb + (size_t)tile * 2048 + q * 1024 + lane * 16) = o;
        }
    }
}

// ============ Hierarchical exclusive scan of cnt3[NCNT] -> off3 ============
extern "C" __global__ void __launch_bounds__(1024)
scanA_kernel(const int* __restrict__ cnt3, int* __restrict__ off3, int* __restrict__ bsum)
{
    __shared__ int sh[1024];
    const int t = threadIdx.x;
    const int i = blockIdx.x * 1024 + t;
    const int v = (i < NCNT) ? cnt3[i] : 0;
    sh[t] = v;
    __syncthreads();
    for (int off = 1; off < 1024; off <<= 1) {
        const int u = (t >= off) ? sh[t - off] : 0;
        __syncthreads();
        sh[t] += u;
        __syncthreads();
    }
    if (i < NCNT) off3[i] = sh[t] - v;
    if (t == 1023) bsum[blockIdx.x] = sh[1023];
}

extern "C" __global__ void __launch_bounds__(128)
scanB_kernel(int* __restrict__ bsum)
{
    __shared__ int sh[128];
    const int t = threadIdx.x;
    const int v = (t < SCANB2) ? bsum[t] : 0;
    sh[t] = v;
    __syncthreads();
    for (int off = 1; off < 128; off <<= 1) {
        const int u = (t >= off) ? sh[t - off] : 0;
        __syncthreads();
        sh[t] += u;
        __syncthreads();
    }
    if (t < SCANB2) bsum[t] = sh[t] - v;
}

extern "C" __global__ void __launch_bounds__(1024)
scanC_kernel(int* __restrict__ off3, const int* __restrict__ bsum)
{
    const int i = blockIdx.x * 1024 + threadIdx.x;
    if (i < NCNT) off3[i] += bsum[blockIdx.x];
}

// ============ Privatized scatter: LDS cursors, zero global atomics ============
extern "C" __global__ void __launch_bounds__(256)
scatter3_kernel(const int* __restrict__ ei, const int* __restrict__ off3,
                unsigned* __restrict__ sedge)
{
    __shared__ int cur[NB];
    const int b   = blockIdx.x;                  // grid must be NBLK
    const int tid = threadIdx.x;
    for (int k = tid; k < NB; k += 256) cur[k] = off3[k * NBLK + b];
    __syncthreads();
    const int i0 = b * EPB;
    for (int i = i0 + tid; i < i0 + EPB; i += 256) {
        const int s = ei[i];
        const int d = ei[NE + i];
        const int pos = atomicAdd(&cur[d >> GSH], 1);   // LDS atomic
        sedge[pos] = (unsigned)s | ((unsigned)(d & (GSZ - 1)) << 17);
    }
}

// ============ Per-bucket exact refinement sort (R6-proven body) ============
extern "C" __global__ void __launch_bounds__(256)
sort2_kernel(const unsigned* __restrict__ sedge, const int* __restrict__ off3,
             int2* __restrict__ spair)
{
    __shared__ int hist[GSZ], base[GSZ], curs[GSZ];
    const int tid = threadIdx.x;
    const int b   = blockIdx.x;
    const int r0  = off3[b * NBLK];
    const int r1  = (b == NB - 1) ? NE : off3[(b + 1) * NBLK];

    if (tid < GSZ) hist[tid] = 0;
    __syncthreads();
    for (int i = r0 + tid; i < r1; i += 256)
        atomicAdd(&hist[(sedge[i] >> 17) & (GSZ - 1)], 1);
    __syncthreads();
    if (tid == 0) {
        int run = 0;
        for (int j = 0; j < GSZ; ++j) { base[j] = run; run += hist[j]; }
    }
    __syncthreads();
    if (tid < GSZ) curs[tid] = base[tid];
    __syncthreads();
    for (int i = r0 + tid; i < r1; i += 256) {
        const unsigned pk = sedge[i];
        const int dl = (pk >> 17) & (GSZ - 1);
        const int pos = r0 + atomicAdd(&curs[dl], 1);
        spair[pos] = make_int2((int)(pk & 0x1FFFFu), (b << GSH) | dl);
    }
}

// ============ Edge kernel (sorted): R6-proven register-run accumulation ====
extern "C" __global__ void __launch_bounds__(256, 2)
edge_kernel_sorted(const unsigned short* __restrict__ Pt, const unsigned short* __restrict__ Pb,
                   const float* __restrict__ x, const int2* __restrict__ spair,
                   const float* __restrict__ We2, const float* __restrict__ be2,
                   const float* __restrict__ Winf, const float* __restrict__ binf,
                   float* __restrict__ mi)
{
    __shared__ float fx[4][1024];
    const int tid  = threadIdx.x;
    const int wib  = tid >> 6;
    const int lane = tid & 63;
    const int e = lane & 15, g = lane >> 4;
    float* fb = &fx[wib][0];
    const int se = ((e & 1) << 4) | ((e >> 1) & 3);

    bf16x8 A2[4][2];
    f32x4 b2r[4], wir[4];
    #pragma unroll
    for (int t = 0; t < 4; ++t) {
        #pragma unroll
        for (int ks = 0; ks < 2; ++ks) {
            bf16x8 a;
            #pragma unroll
            for (int j = 0; j < 8; ++j)
                a[j] = f2bf(We2[(32 * ks + 8 * g + j) * 64 + 16 * t + e]);
            A2[t][ks] = a;
        }
        #pragma unroll
        for (int r = 0; r < 4; ++r) {
            b2r[t][r] = be2[16 * t + 4 * g + r];
            wir[t][r] = Winf[16 * t + 4 * g + r];
        }
    }
    const float binf0 = binf[0];

    const int NT     = NE / 16;
    const int nwaves = gridDim.x * 4;
    const int gwid   = blockIdx.x * 4 + wib;
    const int chunk  = (NT + nwaves - 1) / nwaves;
    const int t0 = gwid * chunk;
    const int t1 = (t0 + chunk < NT) ? t0 + chunk : NT;

    float racc  = 0.f;   // running row accumulator, channel = lane
    int   rrow  = -1;    // wave-uniform current node id

    for (int tile = t0; tile < t1; ++tile) {
        const int eid = tile * 16 + e;
        const int2 sd = spair[eid];
        const int sN = sd.x;
        const int dN = sd.y;

        const float dx = x[dN * 3 + 0] - x[sN * 3 + 0];
        const float dy = x[dN * 3 + 1] - x[sN * 3 + 1];
        const float dz = x[dN * 3 + 2] - x[sN * 3 + 2];
        const float dsq = dx * dx + dy * dy + dz * dz;
        const float edis = sigmoidf_(TEMP / (sqrtf(dsq) + 1e-8f));

        bf16x8 B2[2];
        #pragma unroll
        for (int ks = 0; ks < 2; ++ks) {
            const uint4 ut = *(const uint4*)(Pt + (size_t)dN * 64 + 32 * ks + 8 * g);
            const uint4 ub = *(const uint4*)(Pb + (size_t)sN * 64 + 32 * ks + 8 * g);
            bf16x8 bb;
            unsigned tw, bw;
            tw = ut.x; bw = ub.x;
            bb[0] = f2bf(fmaxf(bf2f(tw & 0xffffu) + bf2f(bw & 0xffffu), 0.f));
            bb[1] = f2bf(fmaxf(bf2f(tw >> 16)     + bf2f(bw >> 16),     0.f));
            tw = ut.y; bw = ub.y;
            bb[2] = f2bf(fmaxf(bf2f(tw & 0xffffu) + bf2f(bw & 0xffffu), 0.f));
            bb[3] = f2bf(fmaxf(bf2f(tw >> 16)     + bf2f(bw >> 16),     0.f));
            tw = ut.z; bw = ub.z;
            bb[4] = f2bf(fmaxf(bf2f(tw & 0xffffu) + bf2f(bw & 0xffffu), 0.f));
            bb[5] = f2bf(fmaxf(bf2f(tw >> 16)     + bf2f(bw >> 16),     0.f));
            tw = ut.w; bw = ub.w;
            bb[6] = f2bf(fmaxf(bf2f(tw & 0xffffu) + bf2f(bw & 0xffffu), 0.f));
            bb[7] = f2bf(fmaxf(bf2f(tw >> 16)     + bf2f(bw >> 16),     0.f));
            B2[ks] = bb;
        }

        f32x4 acc2[4];
        #pragma unroll
        for (int t = 0; t < 4; ++t) {
            acc2[t] = b2r[t];
            #pragma unroll
            for (int ks = 0; ks < 2; ++ks)
                acc2[t] = __builtin_amdgcn_mfma_f32_16x16x32_bf16(A2[t][ks], B2[ks], acc2[t], 0, 0, 0);
        }

        float m[4][4];
        float p = 0.f;
        #pragma unroll
        for (int t = 0; t < 4; ++t)
            #pragma unroll
            for (int r = 0; r < 4; ++r) {
                m[t][r] = fmaxf(acc2[t][r], 0.f);
                p = fmaf(m[t][r], wir[t][r], p);
            }
        p += __shfl_xor(p, 16);
        p += __shfl_xor(p, 32);
        const float w = sigmoidf_((p + binf0) * edis);

        #pragma unroll
        for (int t = 0; t < 4; ++t)
            #pragma unroll
            for (int r = 0; r < 4; ++r)
                fb[e * 64 + ((16 * t + 4 * g + r) ^ se)] = m[t][r] * w;

        #pragma unroll
        for (int i = 0; i < 16; ++i) {
            const int row = __builtin_amdgcn_readlane(dN, i);
            const int si = ((i & 1) << 4) | ((i >> 1) & 3);
            const float v = fb[i * 64 + (lane ^ si)];
            if (row != rrow) {
                if (rrow >= 0) atomicAdd(mi + (size_t)rrow * 64 + lane, racc);
                rrow = row; racc = v;
            } else {
                racc += v;
            }
        }
    }
    if (rrow >= 0) atomicAdd(mi + (size_t)rrow * 64 + lane, racc);
}

// ============ Edge kernel (unsorted fallback, small-ws path) ============
extern "C" __global__ void __launch_bounds__(256, 2)
edge_kernel_unsorted(const unsigned short* __restrict__ Pt, const unsigned short* __restrict__ Pb,
                     const float* __restrict__ x, const int* __restrict__ ei,
                     const float* __restrict__ We2, const float* __restrict__ be2,
                     const float* __restrict__ Winf, const float* __restrict__ binf,
                     float* __restrict__ mi)
{
    __shared__ float fx[4][1024];
    const int tid  = threadIdx.x;
    const int wib  = tid >> 6;
    const int lane = tid & 63;
    const int e = lane & 15, g = lane >> 4;
    float* fb = &fx[wib][0];
    const int se = ((e & 1) << 4) | ((e >> 1) & 3);

    bf16x8 A2[4][2];
    f32x4 b2r[4], wir[4];
    #pragma unroll
    for (int t = 0; t < 4; ++t) {
        #pragma unroll
        for (int ks = 0; ks < 2; ++ks) {
            bf16x8 a;
            #pragma unroll
            for (int j = 0; j < 8; ++j)
                a[j] = f2bf(We2[(32 * ks + 8 * g + j) * 64 + 16 * t + e]);
            A2[t][ks] = a;
        }
        #pragma unroll
        for (int r = 0; r < 4; ++r) {
            b2r[t][r] = be2[16 * t + 4 * g + r];
            wir[t][r] = Winf[16 * t + 4 * g + r];
        }
    }
    const float binf0 = binf[0];

    const int gwid = blockIdx.x * 4 + wib;
    const int nw   = gridDim.x * 4;

    for (int tile = gwid; tile < NE / 16; tile += nw) {
        const int eid = tile * 16 + e;
        const int sN = ei[eid];
        const int dN = ei[NE + eid];

        const float dx = x[dN * 3 + 0] - x[sN * 3 + 0];
        const float dy = x[dN * 3 + 1] - x[sN * 3 + 1];
        const float dz = x[dN * 3 + 2] - x[sN * 3 + 2];
        const float dsq = dx * dx + dy * dy + dz * dz;
        const float edis = sigmoidf_(TEMP / (sqrtf(dsq) + 1e-8f));

        bf16x8 B2[2];
        #pragma unroll
        for (int ks = 0; ks < 2; ++ks) {
            const uint4 ut = *(const uint4*)(Pt + (size_t)dN * 64 + 32 * ks + 8 * g);
            const uint4 ub = *(const uint4*)(Pb + (size_t)sN * 64 + 32 * ks + 8 * g);
            bf16x8 bb;
            unsigned tw, bw;
            tw = ut.x; bw = ub.x;
            bb[0] = f2bf(fmaxf(bf2f(tw & 0xffffu) + bf2f(bw & 0xffffu), 0.f));
            bb[1] = f2bf(fmaxf(bf2f(tw >> 16)     + bf2f(bw >> 16),     0.f));
            tw = ut.y; bw = ub.y;
            bb[2] = f2bf(fmaxf(bf2f(tw & 0xffffu) + bf2f(bw & 0xffffu), 0.f));
            bb[3] = f2bf(fmaxf(bf2f(tw >> 16)     + bf2f(bw >> 16),     0.f));
            tw = ut.z; bw = ub.z;
            bb[4] = f2bf(fmaxf(bf2f(tw & 0xffffu) + bf2f(bw & 0xffffu), 0.f));
            bb[5] = f2bf(fmaxf(bf2f(tw >> 16)     + bf2f(bw >> 16),     0.f));
            tw = ut.w; bw = ub.w;
            bb[6] = f2bf(fmaxf(bf2f(tw & 0xffffu) + bf2f(bw & 0xffffu), 0.f));
            bb[7] = f2bf(fmaxf(bf2f(tw >> 16)     + bf2f(bw >> 16),     0.f));
            B2[ks] = bb;
        }

        f32x4 acc2[4];
        #pragma unroll
        for (int t = 0; t < 4; ++t) {
            acc2[t] = b2r[t];
            #pragma unroll
            for (int ks = 0; ks < 2; ++ks)
                acc2[t] = __builtin_amdgcn_mfma_f32_16x16x32_bf16(A2[t][ks], B2[ks], acc2[t], 0, 0, 0);
        }

        float m[4][4];
        float p = 0.f;
        #pragma unroll
        for (int t = 0; t < 4; ++t)
            #pragma unroll
            for (int r = 0; r < 4; ++r) {
                m[t][r] = fmaxf(acc2[t][r], 0.f);
                p = fmaf(m[t][r], wir[t][r], p);
            }
        p += __shfl_xor(p, 16);
        p += __shfl_xor(p, 32);
        const float w = sigmoidf_((p + binf0) * edis);

        #pragma unroll
        for (int t = 0; t < 4; ++t)
            #pragma unroll
            for (int r = 0; r < 4; ++r)
                fb[e * 64 + ((16 * t + 4 * g + r) ^ se)] = m[t][r] * w;

        #pragma unroll
        for (int i = 0; i < 16; ++i) {
            const int row = __shfl(dN, i);
            const int si = ((i & 1) << 4) | ((i >> 1) & 3);
            const float v = fb[i * 64 + (lane ^ si)];
            atomicAdd(mi + (size_t)row * 64 + lane, v);
        }
    }
}

// ============ Node kernel: same B2B MFMA + residual + LayerNorm =============
extern "C" __global__ void __launch_bounds__(256, 2)
node_kernel(const float* __restrict__ h, const float* __restrict__ mi_,
            const float* __restrict__ Wn1, const float* __restrict__ bn1,
            const float* __restrict__ Wn2, const float* __restrict__ bn2,
            const float* __restrict__ lng, const float* __restrict__ lnb,
            float* __restrict__ out)
{
    __shared__ unsigned xlds[4][16 * 32];
    const int tid  = threadIdx.x;
    const int wib  = tid >> 6;
    const int lane = tid & 63;
    const int e = lane & 15, g = lane >> 4;
    unsigned* tb = &xlds[wib][0];
    const int sw = (e & 7) << 2;

    bf16x8 A1[4][4], A2[4][2];
    f32x4 b1r[4], b2r[4], gr[4], br[4];
    #pragma unroll
    for (int t = 0; t < 4; ++t) {
        #pragma unroll
        for (int ks = 0; ks < 4; ++ks) {
            bf16x8 a;
            #pragma unroll
            for (int j = 0; j < 8; ++j)
                a[j] = f2bf(Wn1[(32 * ks + 8 * g + j) * 64 + 16 * t + e]);
            A1[t][ks] = a;
        }
        #pragma unroll
        for (int ks = 0; ks < 2; ++ks) {
            bf16x8 a;
            #pragma unroll
            for (int j = 0; j < 8; ++j)
                a[j] = f2bf(Wn2[(32 * ks + 8 * g + j) * 64 + 16 * t + e]);
            A2[t][ks] = a;
        }
        #pragma unroll
        for (int r = 0; r < 4; ++r) {
            b1r[t][r] = bn1[16 * t + 4 * g + r];
            b2r[t][r] = bn2[16 * t + 4 * g + r];
            gr[t][r]  = lng[16 * t + 4 * g + r];
            br[t][r]  = lnb[16 * t + 4 * g + r];
        }
    }

    const int gwid = blockIdx.x * 4 + wib;
    const int nw   = gridDim.x * 4;

    for (int tile = gwid; tile < NN / 16; tile += nw) {
        const int node = tile * 16 + e;

        bf16x8 B1[4];
        #pragma unroll
        for (int ks = 0; ks < 4; ++ks) {
            const float* srcp = (ks < 2) ? mi_ : h;
            const float4* p = (const float4*)(srcp + (size_t)node * 64 + (ks & 1) * 32 + 8 * g);
            const float4 f0 = p[0], f1 = p[1];
            bf16x8 b;
            b[0] = f2bf(f0.x); b[1] = f2bf(f0.y); b[2] = f2bf(f0.z); b[3] = f2bf(f0.w);
            b[4] = f2bf(f1.x); b[5] = f2bf(f1.y); b[6] = f2bf(f1.z); b[7] = f2bf(f1.w);
            B1[ks] = b;
        }

        f32x4 acc1[4];
        #pragma unroll
        for (int t = 0; t < 4; ++t) {
            acc1[t] = b1r[t];
            #pragma unroll
            for (int ks = 0; ks < 4; ++ks)
                acc1[t] = __builtin_amdgcn_mfma_f32_16x16x32_bf16(A1[t][ks], B1[ks], acc1[t], 0, 0, 0);
        }

        #pragma unroll
        for (int t = 0; t < 4; ++t) {
            const float r0 = fmaxf(acc1[t][0], 0.f), r1 = fmaxf(acc1[t][1], 0.f);
            const float r2 = fmaxf(acc1[t][2], 0.f), r3 = fmaxf(acc1[t][3], 0.f);
            tb[e * 32 + ((8 * t + 2 * g + 0) ^ sw)] = pk2(r0, r1);
            tb[e * 32 + ((8 * t + 2 * g + 1) ^ sw)] = pk2(r2, r3);
        }
        bf16x8 B2[2];
        #pragma unroll
        for (int ks = 0; ks < 2; ++ks) {
            union { uint4 u; bf16x8 b; } cvt;
            cvt.u = *(const uint4*)&tb[e * 32 + ((16 * ks + 4 * g) ^ sw)];
            B2[ks] = cvt.b;
        }

        f32x4 acc2[4];
        #pragma unroll
        for (int t = 0; t < 4; ++t) {
            acc2[t] = b2r[t];
            #pragma unroll
            for (int ks = 0; ks < 2; ++ks)
                acc2[t] = __builtin_amdgcn_mfma_f32_16x16x32_bf16(A2[t][ks], B2[ks], acc2[t], 0, 0, 0);
        }

        float z[4][4];
        float s1 = 0.f, s2 = 0.f;
        #pragma unroll
        for (int t = 0; t < 4; ++t) {
            const float4 hres = *(const float4*)(h + (size_t)node * 64 + 16 * t + 4 * g);
            #pragma unroll
            for (int r = 0; r < 4; ++r) {
                z[t][r] = acc2[t][r] + hres[r];
                s1 += z[t][r];
                s2 = fmaf(z[t][r], z[t][r], s2);
            }
        }
        s1 += __shfl_xor(s1, 16); s1 += __shfl_xor(s1, 32);
        s2 += __shfl_xor(s2, 16); s2 += __shfl_xor(s2, 32);
        const float mu   = s1 * (1.0f / 64.0f);
        const float var  = s2 * (1.0f / 64.0f) - mu * mu;
        const float rstd = rsqrtf(var + LNEPS);

        #pragma unroll
        for (int t = 0; t < 4; ++t) {
            float4 o;
            #pragma unroll
            for (int r = 0; r < 4; ++r)
                o[r] = (z[t][r] - mu) * rstd * gr[t][r] + br[t][r];
            *(float4*)(out + (size_t)node * 64 + 16 * t + 4 * g) = o;
        }
    }
}

extern "C" void kernel_launch(void* const* d_in, const int* in_sizes, int n_in,
                              void* d_out, int out_size, void* d_ws, size_t ws_size,
                              hipStream_t stream)
{
    const float* h    = (const float*)d_in[0];
    const float* x    = (const float*)d_in[1];
    const int*   ei   = (const int*)d_in[2];
    const float* We1  = (const float*)d_in[3];
    const float* be1  = (const float*)d_in[4];
    const float* We2  = (const float*)d_in[5];
    const float* be2  = (const float*)d_in[6];
    const float* Winf = (const float*)d_in[7];
    const float* binf = (const float*)d_in[8];
    const float* Wn1  = (const float*)d_in[9];
    const float* bn1  = (const float*)d_in[10];
    const float* Wn2  = (const float*)d_in[11];
    const float* bn2  = (const float*)d_in[12];
    const float* lng  = (const float*)d_in[13];
    const float* lnb  = (const float*)d_in[14];
    float* out = (float*)d_out;

    const size_t mi_bytes = (size_t)NN * HDIM * sizeof(float);          // 25.6 MB
    const size_t p_bytes  = (size_t)NN * HDIM * sizeof(unsigned short); // 12.8 MB
    const size_t sp_bytes = (size_t)NE * sizeof(int2);                  // 12.8 MB
    const size_t se_bytes = (size_t)NE * sizeof(unsigned);              //  6.4 MB
    const size_t c3_bytes = (size_t)NCNT * sizeof(int);                 //  0.4 MB

    // sedge/cnt3/off3/bsum all alias mi's scratch (dead before memset(mi))
    const size_t need_sorted = mi_bytes + 2 * p_bytes + sp_bytes;

    if (ws_size >= need_sorted &&
        mi_bytes >= se_bytes + 2 * c3_bytes + SCANB2 * sizeof(int)) {
        char* ws = (char*)d_ws;
        float*          mi    = (float*)ws;              ws += mi_bytes;
        unsigned short* Pt    = (unsigned short*)ws;     ws += p_bytes;
        unsigned short* Pb    = (unsigned short*)ws;     ws += p_bytes;
        int2*           spair = (int2*)ws;

        char* mis = (char*)mi;
        unsigned* sedge = (unsigned*)mis;                          // [0, 6.4 MB)
        int*      cnt3  = (int*)(mis + se_bytes);                  // 0.4 MB
        int*      off3  = (int*)(mis + se_bytes + c3_bytes);       // 0.4 MB
        int*      bsum  = (int*)(mis + se_bytes + 2 * c3_bytes);   // 392 B

        hipMemcpyAsync(out + (size_t)NN * HDIM, x, (size_t)NN * 3 * sizeof(float),
                       hipMemcpyDeviceToDevice, stream);

        front_kernel<<<NBLK + 512, 256, 0, stream>>>(h, We1, be1, Pt, Pb, ei, cnt3);
        scanA_kernel<<<SCANB2, 1024, 0, stream>>>(cnt3, off3, bsum);
        scanB_kernel<<<1, 128, 0, stream>>>(bsum);
        scanC_kernel<<<SCANB2, 1024, 0, stream>>>(off3, bsum);
        scatter3_kernel<<<NBLK, 256, 0, stream>>>(ei, off3, sedge);
        sort2_kernel<<<NB, 256, 0, stream>>>(sedge, off3, spair);
        hipMemsetAsync(mi, 0, mi_bytes, stream);   // after sort2: frees aliases
        edge_kernel_sorted<<<2048, 256, 0, stream>>>(Pt, Pb, x, spair, We2, be2, Winf, binf, mi);
        node_kernel<<<512, 256, 0, stream>>>(h, mi, Wn1, bn1, Wn2, bn2, lng, lnb, out);
    } else {
        float* mi;
        unsigned short* Pt;
        unsigned short* Pb;
        if (ws_size >= mi_bytes + 2 * p_bytes) {
            mi = (float*)d_ws;
            Pt = (unsigned short*)((char*)d_ws + mi_bytes);
            Pb = (unsigned short*)((char*)d_ws + mi_bytes + p_bytes);
        } else {
            mi = out;
            Pt = (unsigned short*)d_ws;
            Pb = (unsigned short*)((char*)d_ws + p_bytes);
        }

        hipMemsetAsync(mi, 0, mi_bytes, stream);
        hipMemcpyAsync(out + (size_t)NN * HDIM, x, (size_t)NN * 3 * sizeof(float),
                       hipMemcpyDeviceToDevice, stream);

        // fallback pre (no front fusion): reuse front_kernel's pre role only
        front_kernel<<<NBLK + 512, 256, 0, stream>>>(h, We1, be1, Pt, Pb, ei,
                                                     (int*)((char*)d_ws));  // cnt3 scratch unused later
        edge_kernel_unsorted<<<2048, 256, 0, stream>>>(Pt, Pb, x, ei, We2, be2, Winf, binf, mi);
        node_kernel<<<512, 256, 0, stream>>>(h, mi, Wn1, bn1, Wn2, bn2, lng, lnb, out);
    }
}

// Round 11
// 196.646 us; speedup vs baseline: 1.7645x; 1.1217x over previous
//
#include <hip/hip_runtime.h>
#include <hip/hip_bf16.h>
#include <hip/hip_fp16.h>
#include <math.h>

#define HDIM 64
#define NN   100000
#define NE   1600000
#define TEMP 30.0f
#define LNEPS 1e-5f

// bucketing: 64 nodes per bucket; privatized sort over 64 exclusive edge ranges
#define GSH   6
#define GSZ   64
#define NB    1563           // ceil(NN/64) buckets
#define NBLK  64             // privatized hist/scatter blocks (exclusive ranges)
#define EPB   (NE / NBLK)    // 25000 edges per block
#define NCNT  (NB * NBLK)    // 100032 per-(bucket,block) counters
#define SCANB2 98            // ceil(NCNT/1024)

typedef __attribute__((ext_vector_type(8))) short bf16x8;
typedef __attribute__((ext_vector_type(4))) float f32x4;
typedef _Float16 __attribute__((ext_vector_type(2))) h2t;

__device__ __forceinline__ short f2bf(float f) {
    __hip_bfloat16 b = __float2bfloat16(f);
    short s; __builtin_memcpy(&s, &b, 2); return s;
}
__device__ __forceinline__ unsigned pk2(float lo, float hi) {
    return (unsigned)(unsigned short)f2bf(lo) | ((unsigned)(unsigned short)f2bf(hi) << 16);
}
__device__ __forceinline__ short f2h(float f) {
    __half h = __float2half(f);
    short s; __builtin_memcpy(&s, &h, 2); return s;
}
__device__ __forceinline__ unsigned pk2h(float lo, float hi) {
    return (unsigned)(unsigned short)f2h(lo) | ((unsigned)(unsigned short)f2h(hi) << 16);
}
// packed fp16 add + relu: v_pk_add_f16 + 3-op sign-mask zeroing
__device__ __forceinline__ unsigned pk_add_relu(unsigned a, unsigned b) {
    h2t x, y;
    __builtin_memcpy(&x, &a, 4); __builtin_memcpy(&y, &b, 4);
    h2t r = x + y;
    unsigned u; __builtin_memcpy(&u, &r, 4);
    const unsigned msk = ((u & 0x80008000u) >> 15) * 0xFFFFu;
    return u & ~msk;
}
__device__ __forceinline__ float sigmoidf_(float z) { return 1.0f / (1.0f + __expf(-z)); }

// ============ Front kernel: privatized hist (64 blocks) || pre (512 blocks) ====
// hist role: LDS histogram of its exclusive 25K-edge range -> non-atomic store.
// pre role: Pt[n]=h@We1_top+be1, Pb[n]=h@We1_bot, stored as FP16 rows (128 B).
extern "C" __global__ void __launch_bounds__(256, 2)
front_kernel(const float* __restrict__ h,
             const float* __restrict__ We1, const float* __restrict__ be1,
             unsigned short* __restrict__ Pt, unsigned short* __restrict__ Pb,
             const int* __restrict__ ei, int* __restrict__ cnt3)
{
    __shared__ float fx[4][1024];    // 16 KB: pre transpose buffers / hist bins
    const int b = blockIdx.x;

    if (b < NBLK) {
        int* hbin = (int*)&fx[0][0];           // 1563 ints (6.25 KB)
        const int tid = threadIdx.x;
        for (int k = tid; k < NB; k += 256) hbin[k] = 0;
        __syncthreads();
        const int i0 = b * EPB;
        for (int i = i0 + tid; i < i0 + EPB; i += 256)
            atomicAdd(&hbin[ei[NE + i] >> GSH], 1);
        __syncthreads();
        for (int k = tid; k < NB; k += 256)
            cnt3[k * NBLK + b] = hbin[k];      // exclusive slot: plain store
        return;
    }

    // ---- pre role ----
    const int pb   = b - NBLK;
    const int tid  = threadIdx.x;
    const int wib  = tid >> 6;
    const int lane = tid & 63;
    const int e = lane & 15, g = lane >> 4;
    float* fb = &fx[wib][0];
    const int se = ((e & 1) << 4) | ((e >> 1) & 3);

    bf16x8 At[4][2], Ab[4][2];
    f32x4 b1r[4];
    #pragma unroll
    for (int t = 0; t < 4; ++t) {
        #pragma unroll
        for (int ks = 0; ks < 2; ++ks) {
            bf16x8 a, bb;
            #pragma unroll
            for (int j = 0; j < 8; ++j) {
                a[j]  = f2bf(We1[(32 * ks + 8 * g + j) * 64 + 16 * t + e]);
                bb[j] = f2bf(We1[(64 + 32 * ks + 8 * g + j) * 64 + 16 * t + e]);
            }
            At[t][ks] = a; Ab[t][ks] = bb;
        }
        #pragma unroll
        for (int r = 0; r < 4; ++r) b1r[t][r] = be1[16 * t + 4 * g + r];
    }

    const int gwid = pb * 4 + wib;
    const int nw   = 512 * 4;

    for (int tile = gwid; tile < NN / 16; tile += nw) {
        const int node = tile * 16 + e;

        bf16x8 B[2];
        #pragma unroll
        for (int ks = 0; ks < 2; ++ks) {
            const float4* p = (const float4*)(h + (size_t)node * 64 + ks * 32 + 8 * g);
            const float4 f0 = p[0], f1 = p[1];
            bf16x8 bb;
            bb[0] = f2bf(f0.x); bb[1] = f2bf(f0.y); bb[2] = f2bf(f0.z); bb[3] = f2bf(f0.w);
            bb[4] = f2bf(f1.x); bb[5] = f2bf(f1.y); bb[6] = f2bf(f1.z); bb[7] = f2bf(f1.w);
            B[ks] = bb;
        }

        f32x4 aT[4], aB[4];
        #pragma unroll
        for (int t = 0; t < 4; ++t) {
            aT[t] = b1r[t];
            aB[t] = (f32x4){0.f, 0.f, 0.f, 0.f};
            #pragma unroll
            for (int ks = 0; ks < 2; ++ks) {
                aT[t] = __builtin_amdgcn_mfma_f32_16x16x32_bf16(At[t][ks], B[ks], aT[t], 0, 0, 0);
                aB[t] = __builtin_amdgcn_mfma_f32_16x16x32_bf16(Ab[t][ks], B[ks], aB[t], 0, 0, 0);
            }
        }

        #pragma unroll
        for (int t = 0; t < 4; ++t)
            #pragma unroll
            for (int r = 0; r < 4; ++r)
                fb[e * 64 + ((16 * t + 4 * g + r) ^ se)] = aT[t][r];
        #pragma unroll
        for (int q = 0; q < 2; ++q) {
            const int row = q * 8 + (lane >> 3);
            const int sr  = ((row & 1) << 4) | ((row >> 1) & 3);
            const int c0  = (lane & 7) * 8;
            uint4 o;
            o.x = pk2h(fb[row * 64 + ((c0 + 0) ^ sr)], fb[row * 64 + ((c0 + 1) ^ sr)]);
            o.y = pk2h(fb[row * 64 + ((c0 + 2) ^ sr)], fb[row * 64 + ((c0 + 3) ^ sr)]);
            o.z = pk2h(fb[row * 64 + ((c0 + 4) ^ sr)], fb[row * 64 + ((c0 + 5) ^ sr)]);
            o.w = pk2h(fb[row * 64 + ((c0 + 6) ^ sr)], fb[row * 64 + ((c0 + 7) ^ sr)]);
            *(uint4*)((char*)Pt + (size_t)tile * 2048 + q * 1024 + lane * 16) = o;
        }

        #pragma unroll
        for (int t = 0; t < 4; ++t)
            #pragma unroll
            for (int r = 0; r < 4; ++r)
                fb[e * 64 + ((16 * t + 4 * g + r) ^ se)] = aB[t][r];
        #pragma unroll
        for (int q = 0; q < 2; ++q) {
            const int row = q * 8 + (lane >> 3);
            const int sr  = ((row & 1) << 4) | ((row >> 1) & 3);
            const int c0  = (lane & 7) * 8;
            uint4 o;
            o.x = pk2h(fb[row * 64 + ((c0 + 0) ^ sr)], fb[row * 64 + ((c0 + 1) ^ sr)]);
            o.y = pk2h(fb[row * 64 + ((c0 + 2) ^ sr)], fb[row * 64 + ((c0 + 3) ^ sr)]);
            o.z = pk2h(fb[row * 64 + ((c0 + 4) ^ sr)], fb[row * 64 + ((c0 + 5) ^ sr)]);
            o.w = pk2h(fb[row * 64 + ((c0 + 6) ^ sr)], fb[row * 64 + ((c0 + 7) ^ sr)]);
            *(uint4*)((char*)Pb + (size_t)tile * 2048 + q * 1024 + lane * 16) = o;
        }
    }
}

// ============ Hierarchical exclusive scan of cnt3[NCNT] -> off3 ============
extern "C" __global__ void __launch_bounds__(1024)
scanA_kernel(const int* __restrict__ cnt3, int* __restrict__ off3, int* __restrict__ bsum)
{
    __shared__ int sh[1024];
    const int t = threadIdx.x;
    const int i = blockIdx.x * 1024 + t;
    const int v = (i < NCNT) ? cnt3[i] : 0;
    sh[t] = v;
    __syncthreads();
    for (int off = 1; off < 1024; off <<= 1) {
        const int u = (t >= off) ? sh[t - off] : 0;
        __syncthreads();
        sh[t] += u;
        __syncthreads();
    }
    if (i < NCNT) off3[i] = sh[t] - v;
    if (t == 1023) bsum[blockIdx.x] = sh[1023];
}

extern "C" __global__ void __launch_bounds__(128)
scanB_kernel(int* __restrict__ bsum)
{
    __shared__ int sh[128];
    const int t = threadIdx.x;
    const int v = (t < SCANB2) ? bsum[t] : 0;
    sh[t] = v;
    __syncthreads();
    for (int off = 1; off < 128; off <<= 1) {
        const int u = (t >= off) ? sh[t - off] : 0;
        __syncthreads();
        sh[t] += u;
        __syncthreads();
    }
    if (t < SCANB2) bsum[t] = sh[t] - v;
}

extern "C" __global__ void __launch_bounds__(1024)
scanC_kernel(int* __restrict__ off3, const int* __restrict__ bsum)
{
    const int i = blockIdx.x * 1024 + threadIdx.x;
    if (i < NCNT) off3[i] += bsum[blockIdx.x];
}

// ============ Privatized scatter: LDS cursors, zero global atomics ============
extern "C" __global__ void __launch_bounds__(1024)
scatter3_kernel(const int* __restrict__ ei, const int* __restrict__ off3,
                unsigned* __restrict__ sedge)
{
    __shared__ int cur[NB];
    const int b   = blockIdx.x;                  // grid must be NBLK
    const int tid = threadIdx.x;
    for (int k = tid; k < NB; k += 1024) cur[k] = off3[k * NBLK + b];
    __syncthreads();
    const int i0 = b * EPB;
    for (int i = i0 + tid; i < i0 + EPB; i += 1024) {
        const int s = ei[i];
        const int d = ei[NE + i];
        const int pos = atomicAdd(&cur[d >> GSH], 1);   // LDS atomic
        sedge[pos] = (unsigned)s | ((unsigned)(d & (GSZ - 1)) << 17);
    }
}

// ============ Per-bucket exact refinement sort ============
extern "C" __global__ void __launch_bounds__(256)
sort2_kernel(const unsigned* __restrict__ sedge, const int* __restrict__ off3,
             int2* __restrict__ spair)
{
    __shared__ int hist[GSZ], base[GSZ], curs[GSZ];
    const int tid = threadIdx.x;
    const int b   = blockIdx.x;
    const int r0  = off3[b * NBLK];
    const int r1  = (b == NB - 1) ? NE : off3[(b + 1) * NBLK];

    if (tid < GSZ) hist[tid] = 0;
    __syncthreads();
    for (int i = r0 + tid; i < r1; i += 256)
        atomicAdd(&hist[(sedge[i] >> 17) & (GSZ - 1)], 1);
    __syncthreads();
    if (tid == 0) {
        int run = 0;
        for (int j = 0; j < GSZ; ++j) { base[j] = run; run += hist[j]; }
    }
    __syncthreads();
    if (tid < GSZ) curs[tid] = base[tid];
    __syncthreads();
    for (int i = r0 + tid; i < r1; i += 256) {
        const unsigned pk = sedge[i];
        const int dl = (pk >> 17) & (GSZ - 1);
        const int pos = r0 + atomicAdd(&curs[dl], 1);
        spair[pos] = make_int2((int)(pk & 0x1FFFFu), (b << GSH) | dl);
    }
}

// ============ Edge kernel (sorted): register-run accumulation, fp16 P ====
extern "C" __global__ void __launch_bounds__(256, 2)
edge_kernel_sorted(const unsigned short* __restrict__ Pt, const unsigned short* __restrict__ Pb,
                   const float* __restrict__ x, const int2* __restrict__ spair,
                   const float* __restrict__ We2, const float* __restrict__ be2,
                   const float* __restrict__ Winf, const float* __restrict__ binf,
                   float* __restrict__ mi)
{
    __shared__ float fx[4][1024];
    const int tid  = threadIdx.x;
    const int wib  = tid >> 6;
    const int lane = tid & 63;
    const int e = lane & 15, g = lane >> 4;
    float* fb = &fx[wib][0];
    const int s2  = (e >> 1) & 3;          // low swizzle bits (in-block permute)
    const int b16 = (e & 1) << 4;          // high swizzle bit (block select)

    bf16x8 A2[4][2];                        // fp16 fragments (8 halves / 4 VGPRs)
    f32x4 b2r[4], wir[4];
    #pragma unroll
    for (int t = 0; t < 4; ++t) {
        #pragma unroll
        for (int ks = 0; ks < 2; ++ks) {
            bf16x8 a;
            #pragma unroll
            for (int j = 0; j < 8; ++j)
                a[j] = f2h(We2[(32 * ks + 8 * g + j) * 64 + 16 * t + e]);
            A2[t][ks] = a;
        }
        #pragma unroll
        for (int r = 0; r < 4; ++r) {
            b2r[t][r] = be2[16 * t + 4 * g + r];
            wir[t][r] = Winf[16 * t + 4 * g + r];
        }
    }
    const float binf0 = binf[0];

    const int NT     = NE / 16;
    const int nwaves = gridDim.x * 4;
    const int gwid   = blockIdx.x * 4 + wib;
    const int chunk  = (NT + nwaves - 1) / nwaves;
    const int t0 = gwid * chunk;
    const int t1 = (t0 + chunk < NT) ? t0 + chunk : NT;

    float racc  = 0.f;   // running row accumulator, channel = lane
    int   rrow  = -1;    // wave-uniform current node id

    for (int tile = t0; tile < t1; ++tile) {
        const int eid = tile * 16 + e;
        const int2 sd = spair[eid];
        const int sN = sd.x;
        const int dN = sd.y;

        const float dx = x[dN * 3 + 0] - x[sN * 3 + 0];
        const float dy = x[dN * 3 + 1] - x[sN * 3 + 1];
        const float dz = x[dN * 3 + 2] - x[sN * 3 + 2];
        const float dsq = dx * dx + dy * dy + dz * dz;
        const float edis = sigmoidf_(TEMP / (sqrtf(dsq) + 1e-8f));

        // B2 frags: relu(Pt[dst] + Pb[src]) in packed fp16 (1 pk_add + 3-op relu / pair)
        bf16x8 B2[2];
        #pragma unroll
        for (int ks = 0; ks < 2; ++ks) {
            const uint4 ut = *(const uint4*)(Pt + (size_t)dN * 64 + 32 * ks + 8 * g);
            const uint4 ub = *(const uint4*)(Pb + (size_t)sN * 64 + 32 * ks + 8 * g);
            union { uint4 u; bf16x8 b; } cvt;
            cvt.u.x = pk_add_relu(ut.x, ub.x);
            cvt.u.y = pk_add_relu(ut.y, ub.y);
            cvt.u.z = pk_add_relu(ut.z, ub.z);
            cvt.u.w = pk_add_relu(ut.w, ub.w);
            B2[ks] = cvt.b;
        }

        f32x4 acc2[4];
        #pragma unroll
        for (int t = 0; t < 4; ++t) {
            acc2[t] = b2r[t];
            #pragma unroll
            for (int ks = 0; ks < 2; ++ks)
                acc2[t] = __builtin_amdgcn_mfma_f32_16x16x32_f16(A2[t][ks], B2[ks], acc2[t], 0, 0, 0);
        }

        float m[4][4];
        float p = 0.f;
        #pragma unroll
        for (int t = 0; t < 4; ++t)
            #pragma unroll
            for (int r = 0; r < 4; ++r) {
                m[t][r] = fmaxf(acc2[t][r], 0.f);
                p = fmaf(m[t][r], wir[t][r], p);
            }
        p += __shfl_xor(p, 16);
        p += __shfl_xor(p, 32);
        const float w = sigmoidf_((p + binf0) * edis);

        // transpose via 4x ds_write_b128: register XOR-permute (j^s2), block ^b16
        #pragma unroll
        for (int t = 0; t < 4; ++t) {
            const float a0 = m[t][0] * w, a1 = m[t][1] * w;
            const float a2 = m[t][2] * w, a3 = m[t][3] * w;
            const bool sA = (s2 & 1), sB = (s2 & 2);
            const float u0 = sA ? a1 : a0, u1 = sA ? a0 : a1;
            const float u2 = sA ? a3 : a2, u3 = sA ? a2 : a3;
            float4 v;
            v.x = sB ? u2 : u0; v.y = sB ? u3 : u1;
            v.z = sB ? u0 : u2; v.w = sB ? u1 : u3;
            *(float4*)&fb[e * 64 + ((16 * t + 4 * g) ^ b16)] = v;
        }

        #pragma unroll
        for (int i = 0; i < 16; ++i) {
            const int row = __builtin_amdgcn_readlane(dN, i);
            const int si = ((i & 1) << 4) | ((i >> 1) & 3);
            const float v = fb[i * 64 + (lane ^ si)];
            if (row != rrow) {
                if (rrow >= 0) atomicAdd(mi + (size_t)rrow * 64 + lane, racc);
                rrow = row; racc = v;
            } else {
                racc += v;
            }
        }
    }
    if (rrow >= 0) atomicAdd(mi + (size_t)rrow * 64 + lane, racc);
}

// ============ Edge kernel (unsorted fallback, small-ws path) ============
extern "C" __global__ void __launch_bounds__(256, 2)
edge_kernel_unsorted(const unsigned short* __restrict__ Pt, const unsigned short* __restrict__ Pb,
                     const float* __restrict__ x, const int* __restrict__ ei,
                     const float* __restrict__ We2, const float* __restrict__ be2,
                     const float* __restrict__ Winf, const float* __restrict__ binf,
                     float* __restrict__ mi)
{
    __shared__ float fx[4][1024];
    const int tid  = threadIdx.x;
    const int wib  = tid >> 6;
    const int lane = tid & 63;
    const int e = lane & 15, g = lane >> 4;
    float* fb = &fx[wib][0];
    const int se = ((e & 1) << 4) | ((e >> 1) & 3);

    bf16x8 A2[4][2];
    f32x4 b2r[4], wir[4];
    #pragma unroll
    for (int t = 0; t < 4; ++t) {
        #pragma unroll
        for (int ks = 0; ks < 2; ++ks) {
            bf16x8 a;
            #pragma unroll
            for (int j = 0; j < 8; ++j)
                a[j] = f2h(We2[(32 * ks + 8 * g + j) * 64 + 16 * t + e]);
            A2[t][ks] = a;
        }
        #pragma unroll
        for (int r = 0; r < 4; ++r) {
            b2r[t][r] = be2[16 * t + 4 * g + r];
            wir[t][r] = Winf[16 * t + 4 * g + r];
        }
    }
    const float binf0 = binf[0];

    const int gwid = blockIdx.x * 4 + wib;
    const int nw   = gridDim.x * 4;

    for (int tile = gwid; tile < NE / 16; tile += nw) {
        const int eid = tile * 16 + e;
        const int sN = ei[eid];
        const int dN = ei[NE + eid];

        const float dx = x[dN * 3 + 0] - x[sN * 3 + 0];
        const float dy = x[dN * 3 + 1] - x[sN * 3 + 1];
        const float dz = x[dN * 3 + 2] - x[sN * 3 + 2];
        const float dsq = dx * dx + dy * dy + dz * dz;
        const float edis = sigmoidf_(TEMP / (sqrtf(dsq) + 1e-8f));

        bf16x8 B2[2];
        #pragma unroll
        for (int ks = 0; ks < 2; ++ks) {
            const uint4 ut = *(const uint4*)(Pt + (size_t)dN * 64 + 32 * ks + 8 * g);
            const uint4 ub = *(const uint4*)(Pb + (size_t)sN * 64 + 32 * ks + 8 * g);
            union { uint4 u; bf16x8 b; } cvt;
            cvt.u.x = pk_add_relu(ut.x, ub.x);
            cvt.u.y = pk_add_relu(ut.y, ub.y);
            cvt.u.z = pk_add_relu(ut.z, ub.z);
            cvt.u.w = pk_add_relu(ut.w, ub.w);
            B2[ks] = cvt.b;
        }

        f32x4 acc2[4];
        #pragma unroll
        for (int t = 0; t < 4; ++t) {
            acc2[t] = b2r[t];
            #pragma unroll
            for (int ks = 0; ks < 2; ++ks)
                acc2[t] = __builtin_amdgcn_mfma_f32_16x16x32_f16(A2[t][ks], B2[ks], acc2[t], 0, 0, 0);
        }

        float m[4][4];
        float p = 0.f;
        #pragma unroll
        for (int t = 0; t < 4; ++t)
            #pragma unroll
            for (int r = 0; r < 4; ++r) {
                m[t][r] = fmaxf(acc2[t][r], 0.f);
                p = fmaf(m[t][r], wir[t][r], p);
            }
        p += __shfl_xor(p, 16);
        p += __shfl_xor(p, 32);
        const float w = sigmoidf_((p + binf0) * edis);

        #pragma unroll
        for (int t = 0; t < 4; ++t)
            #pragma unroll
            for (int r = 0; r < 4; ++r)
                fb[e * 64 + ((16 * t + 4 * g + r) ^ se)] = m[t][r] * w;

        #pragma unroll
        for (int i = 0; i < 16; ++i) {
            const int row = __shfl(dN, i);
            const int si = ((i & 1) << 4) | ((i >> 1) & 3);
            const float v = fb[i * 64 + (lane ^ si)];
            atomicAdd(mi + (size_t)row * 64 + lane, v);
        }
    }
}

// ============ Node kernel: same B2B MFMA + residual + LayerNorm =============
extern "C" __global__ void __launch_bounds__(256, 2)
node_kernel(const float* __restrict__ h, const float* __restrict__ mi_,
            const float* __restrict__ Wn1, const float* __restrict__ bn1,
            const float* __restrict__ Wn2, const float* __restrict__ bn2,
            const float* __restrict__ lng, const float* __restrict__ lnb,
            float* __restrict__ out)
{
    __shared__ unsigned xlds[4][16 * 32];
    const int tid  = threadIdx.x;
    const int wib  = tid >> 6;
    const int lane = tid & 63;
    const int e = lane & 15, g = lane >> 4;
    unsigned* tb = &xlds[wib][0];
    const int sw = (e & 7) << 2;

    bf16x8 A1[4][4], A2[4][2];
    f32x4 b1r[4], b2r[4], gr[4], br[4];
    #pragma unroll
    for (int t = 0; t < 4; ++t) {
        #pragma unroll
        for (int ks = 0; ks < 4; ++ks) {
            bf16x8 a;
            #pragma unroll
            for (int j = 0; j < 8; ++j)
                a[j] = f2bf(Wn1[(32 * ks + 8 * g + j) * 64 + 16 * t + e]);
            A1[t][ks] = a;
        }
        #pragma unroll
        for (int ks = 0; ks < 2; ++ks) {
            bf16x8 a;
            #pragma unroll
            for (int j = 0; j < 8; ++j)
                a[j] = f2bf(Wn2[(32 * ks + 8 * g + j) * 64 + 16 * t + e]);
            A2[t][ks] = a;
        }
        #pragma unroll
        for (int r = 0; r < 4; ++r) {
            b1r[t][r] = bn1[16 * t + 4 * g + r];
            b2r[t][r] = bn2[16 * t + 4 * g + r];
            gr[t][r]  = lng[16 * t + 4 * g + r];
            br[t][r]  = lnb[16 * t + 4 * g + r];
        }
    }

    const int gwid = blockIdx.x * 4 + wib;
    const int nw   = gridDim.x * 4;

    for (int tile = gwid; tile < NN / 16; tile += nw) {
        const int node = tile * 16 + e;

        bf16x8 B1[4];
        #pragma unroll
        for (int ks = 0; ks < 4; ++ks) {
            const float* srcp = (ks < 2) ? mi_ : h;
            const float4* p = (const float4*)(srcp + (size_t)node * 64 + (ks & 1) * 32 + 8 * g);
            const float4 f0 = p[0], f1 = p[1];
            bf16x8 b;
            b[0] = f2bf(f0.x); b[1] = f2bf(f0.y); b[2] = f2bf(f0.z); b[3] = f2bf(f0.w);
            b[4] = f2bf(f1.x); b[5] = f2bf(f1.y); b[6] = f2bf(f1.z); b[7] = f2bf(f1.w);
            B1[ks] = b;
        }

        f32x4 acc1[4];
        #pragma unroll
        for (int t = 0; t < 4; ++t) {
            acc1[t] = b1r[t];
            #pragma unroll
            for (int ks = 0; ks < 4; ++ks)
                acc1[t] = __builtin_amdgcn_mfma_f32_16x16x32_bf16(A1[t][ks], B1[ks], acc1[t], 0, 0, 0);
        }

        #pragma unroll
        for (int t = 0; t < 4; ++t) {
            const float r0 = fmaxf(acc1[t][0], 0.f), r1 = fmaxf(acc1[t][1], 0.f);
            const float r2 = fmaxf(acc1[t][2], 0.f), r3 = fmaxf(acc1[t][3], 0.f);
            tb[e * 32 + ((8 * t + 2 * g + 0) ^ sw)] = pk2(r0, r1);
            tb[e * 32 + ((8 * t + 2 * g + 1) ^ sw)] = pk2(r2, r3);
        }
        bf16x8 B2[2];
        #pragma unroll
        for (int ks = 0; ks < 2; ++ks) {
            union { uint4 u; bf16x8 b; } cvt;
            cvt.u = *(const uint4*)&tb[e * 32 + ((16 * ks + 4 * g) ^ sw)];
            B2[ks] = cvt.b;
        }

        f32x4 acc2[4];
        #pragma unroll
        for (int t = 0; t < 4; ++t) {
            acc2[t] = b2r[t];
            #pragma unroll
            for (int ks = 0; ks < 2; ++ks)
                acc2[t] = __builtin_amdgcn_mfma_f32_16x16x32_bf16(A2[t][ks], B2[ks], acc2[t], 0, 0, 0);
        }

        float z[4][4];
        float s1 = 0.f, s2 = 0.f;
        #pragma unroll
        for (int t = 0; t < 4; ++t) {
            const float4 hres = *(const float4*)(h + (size_t)node * 64 + 16 * t + 4 * g);
            #pragma unroll
            for (int r = 0; r < 4; ++r) {
                z[t][r] = acc2[t][r] + hres[r];
                s1 += z[t][r];
                s2 = fmaf(z[t][r], z[t][r], s2);
            }
        }
        s1 += __shfl_xor(s1, 16); s1 += __shfl_xor(s1, 32);
        s2 += __shfl_xor(s2, 16); s2 += __shfl_xor(s2, 32);
        const float mu   = s1 * (1.0f / 64.0f);
        const float var  = s2 * (1.0f / 64.0f) - mu * mu;
        const float rstd = rsqrtf(var + LNEPS);

        #pragma unroll
        for (int t = 0; t < 4; ++t) {
            float4 o;
            #pragma unroll
            for (int r = 0; r < 4; ++r)
                o[r] = (z[t][r] - mu) * rstd * gr[t][r] + br[t][r];
            *(float4*)(out + (size_t)node * 64 + 16 * t + 4 * g) = o;
        }
    }
}

extern "C" void kernel_launch(void* const* d_in, const int* in_sizes, int n_in,
                              void* d_out, int out_size, void* d_ws, size_t ws_size,
                              hipStream_t stream)
{
    const float* h    = (const float*)d_in[0];
    const float* x    = (const float*)d_in[1];
    const int*   ei   = (const int*)d_in[2];
    const float* We1  = (const float*)d_in[3];
    const float* be1  = (const float*)d_in[4];
    const float* We2  = (const float*)d_in[5];
    const float* be2  = (const float*)d_in[6];
    const float* Winf = (const float*)d_in[7];
    const float* binf = (const float*)d_in[8];
    const float* Wn1  = (const float*)d_in[9];
    const float* bn1  = (const float*)d_in[10];
    const float* Wn2  = (const float*)d_in[11];
    const float* bn2  = (const float*)d_in[12];
    const float* lng  = (const float*)d_in[13];
    const float* lnb  = (const float*)d_in[14];
    float* out = (float*)d_out;

    const size_t mi_bytes = (size_t)NN * HDIM * sizeof(float);          // 25.6 MB
    const size_t p_bytes  = (size_t)NN * HDIM * sizeof(unsigned short); // 12.8 MB
    const size_t sp_bytes = (size_t)NE * sizeof(int2);                  // 12.8 MB
    const size_t se_bytes = (size_t)NE * sizeof(unsigned);              //  6.4 MB
    const size_t c3_bytes = (size_t)NCNT * sizeof(int);                 //  0.4 MB

    // sedge/cnt3/off3/bsum all alias mi's scratch (dead before memset(mi))
    const size_t need_sorted = mi_bytes + 2 * p_bytes + sp_bytes;

    if (ws_size >= need_sorted &&
        mi_bytes >= se_bytes + 2 * c3_bytes + SCANB2 * sizeof(int)) {
        char* ws = (char*)d_ws;
        float*          mi    = (float*)ws;              ws += mi_bytes;
        unsigned short* Pt    = (unsigned short*)ws;     ws += p_bytes;
        unsigned short* Pb    = (unsigned short*)ws;     ws += p_bytes;
        int2*           spair = (int2*)ws;

        char* mis = (char*)mi;
        unsigned* sedge = (unsigned*)mis;                          // [0, 6.4 MB)
        int*      cnt3  = (int*)(mis + se_bytes);                  // 0.4 MB
        int*      off3  = (int*)(mis + se_bytes + c3_bytes);       // 0.4 MB
        int*      bsum  = (int*)(mis + se_bytes + 2 * c3_bytes);   // 392 B

        hipMemcpyAsync(out + (size_t)NN * HDIM, x, (size_t)NN * 3 * sizeof(float),
                       hipMemcpyDeviceToDevice, stream);

        front_kernel<<<NBLK + 512, 256, 0, stream>>>(h, We1, be1, Pt, Pb, ei, cnt3);
        scanA_kernel<<<SCANB2, 1024, 0, stream>>>(cnt3, off3, bsum);
        scanB_kernel<<<1, 128, 0, stream>>>(bsum);
        scanC_kernel<<<SCANB2, 1024, 0, stream>>>(off3, bsum);
        scatter3_kernel<<<NBLK, 1024, 0, stream>>>(ei, off3, sedge);
        sort2_kernel<<<NB, 256, 0, stream>>>(sedge, off3, spair);
        hipMemsetAsync(mi, 0, mi_bytes, stream);   // after sort2: frees aliases
        edge_kernel_sorted<<<2048, 256, 0, stream>>>(Pt, Pb, x, spair, We2, be2, Winf, binf, mi);
        node_kernel<<<512, 256, 0, stream>>>(h, mi, Wn1, bn1, Wn2, bn2, lng, lnb, out);
    } else {
        float* mi;
        unsigned short* Pt;
        unsigned short* Pb;
        if (ws_size >= mi_bytes + 2 * p_bytes) {
            mi = (float*)d_ws;
            Pt = (unsigned short*)((char*)d_ws + mi_bytes);
            Pb = (unsigned short*)((char*)d_ws + mi_bytes + p_bytes);
        } else {
            mi = out;
            Pt = (unsigned short*)d_ws;
            Pb = (unsigned short*)((char*)d_ws + p_bytes);
        }

        hipMemsetAsync(mi, 0, mi_bytes, stream);
        hipMemcpyAsync(out + (size_t)NN * HDIM, x, (size_t)NN * 3 * sizeof(float),
                       hipMemcpyDeviceToDevice, stream);

        front_kernel<<<NBLK + 512, 256, 0, stream>>>(h, We1, be1, Pt, Pb, ei,
                                                     (int*)((char*)d_ws));  // cnt3 scratch unused later
        edge_kernel_unsorted<<<2048, 256, 0, stream>>>(Pt, Pb, x, ei, We2, be2, Winf, binf, mi);
        node_kernel<<<512, 256, 0, stream>>>(h, mi, Wn1, bn1, Wn2, bn2, lng, lnb, out);
    }
}

// Round 12
// 191.957 us; speedup vs baseline: 1.8076x; 1.0244x over previous
//
#include <hip/hip_runtime.h>
#include <hip/hip_bf16.h>
#include <hip/hip_fp16.h>
#include <math.h>

#define HDIM 64
#define NN   100000
#define NE   1600000
#define TEMP 30.0f
#define LNEPS 1e-5f

// bucketing: 64 nodes per bucket; privatized sort over 64 exclusive edge ranges
#define GSH   6
#define GSZ   64
#define NB    1563           // ceil(NN/64) buckets
#define NBLK  64             // privatized hist/scatter blocks (exclusive ranges)
#define EPB   (NE / NBLK)    // 25000 edges per block
#define NCNT  (NB * NBLK)    // 100032 per-(bucket,block) counters
#define SCANB2 98            // ceil(NCNT/1024)
#define FSTR  72             // padded LDS row stride (words): conflict-free b128

typedef __attribute__((ext_vector_type(8))) short bf16x8;
typedef __attribute__((ext_vector_type(4))) float f32x4;
typedef _Float16 __attribute__((ext_vector_type(2))) h2t;

__device__ __forceinline__ short f2bf(float f) {
    __hip_bfloat16 b = __float2bfloat16(f);
    short s; __builtin_memcpy(&s, &b, 2); return s;
}
__device__ __forceinline__ unsigned pk2(float lo, float hi) {
    return (unsigned)(unsigned short)f2bf(lo) | ((unsigned)(unsigned short)f2bf(hi) << 16);
}
__device__ __forceinline__ short f2h(float f) {
    __half h = __float2half(f);
    short s; __builtin_memcpy(&s, &h, 2); return s;
}
__device__ __forceinline__ unsigned pk2h(float lo, float hi) {
    return (unsigned)(unsigned short)f2h(lo) | ((unsigned)(unsigned short)f2h(hi) << 16);
}
// packed fp16 add + relu: v_pk_add_f16 + 3-op sign-mask zeroing
__device__ __forceinline__ unsigned pk_add_relu(unsigned a, unsigned b) {
    h2t x, y;
    __builtin_memcpy(&x, &a, 4); __builtin_memcpy(&y, &b, 4);
    h2t r = x + y;
    unsigned u; __builtin_memcpy(&u, &r, 4);
    const unsigned msk = ((u & 0x80008000u) >> 15) * 0xFFFFu;
    return u & ~msk;
}
__device__ __forceinline__ float sigmoidf_(float z) { return 1.0f / (1.0f + __expf(-z)); }

// ============ Front kernel: privatized hist (64 blocks) || pre (512 blocks) ====
// hist role: LDS histogram of its exclusive 25K-edge range -> non-atomic store.
// pre role: Pt[n]=h@We1_top+be1, Pb[n]=h@We1_bot, stored as FP16 rows (128 B).
extern "C" __global__ void __launch_bounds__(256, 2)
front_kernel(const float* __restrict__ h,
             const float* __restrict__ We1, const float* __restrict__ be1,
             unsigned short* __restrict__ Pt, unsigned short* __restrict__ Pb,
             const int* __restrict__ ei, int* __restrict__ cnt3)
{
    __shared__ float fx[4][1024];    // 16 KB: pre transpose buffers / hist bins
    const int b = blockIdx.x;

    if (b < NBLK) {
        int* hbin = (int*)&fx[0][0];           // 1563 ints (6.25 KB)
        const int tid = threadIdx.x;
        for (int k = tid; k < NB; k += 256) hbin[k] = 0;
        __syncthreads();
        const int i0 = b * EPB;
        for (int i = i0 + tid; i < i0 + EPB; i += 256)
            atomicAdd(&hbin[ei[NE + i] >> GSH], 1);
        __syncthreads();
        for (int k = tid; k < NB; k += 256)
            cnt3[k * NBLK + b] = hbin[k];      // exclusive slot: plain store
        return;
    }

    // ---- pre role ----
    const int pb   = b - NBLK;
    const int tid  = threadIdx.x;
    const int wib  = tid >> 6;
    const int lane = tid & 63;
    const int e = lane & 15, g = lane >> 4;
    float* fb = &fx[wib][0];
    const int se = ((e & 1) << 4) | ((e >> 1) & 3);

    bf16x8 At[4][2], Ab[4][2];
    f32x4 b1r[4];
    #pragma unroll
    for (int t = 0; t < 4; ++t) {
        #pragma unroll
        for (int ks = 0; ks < 2; ++ks) {
            bf16x8 a, bb;
            #pragma unroll
            for (int j = 0; j < 8; ++j) {
                a[j]  = f2bf(We1[(32 * ks + 8 * g + j) * 64 + 16 * t + e]);
                bb[j] = f2bf(We1[(64 + 32 * ks + 8 * g + j) * 64 + 16 * t + e]);
            }
            At[t][ks] = a; Ab[t][ks] = bb;
        }
        #pragma unroll
        for (int r = 0; r < 4; ++r) b1r[t][r] = be1[16 * t + 4 * g + r];
    }

    const int gwid = pb * 4 + wib;
    const int nw   = 512 * 4;

    for (int tile = gwid; tile < NN / 16; tile += nw) {
        const int node = tile * 16 + e;

        bf16x8 B[2];
        #pragma unroll
        for (int ks = 0; ks < 2; ++ks) {
            const float4* p = (const float4*)(h + (size_t)node * 64 + ks * 32 + 8 * g);
            const float4 f0 = p[0], f1 = p[1];
            bf16x8 bb;
            bb[0] = f2bf(f0.x); bb[1] = f2bf(f0.y); bb[2] = f2bf(f0.z); bb[3] = f2bf(f0.w);
            bb[4] = f2bf(f1.x); bb[5] = f2bf(f1.y); bb[6] = f2bf(f1.z); bb[7] = f2bf(f1.w);
            B[ks] = bb;
        }

        f32x4 aT[4], aB[4];
        #pragma unroll
        for (int t = 0; t < 4; ++t) {
            aT[t] = b1r[t];
            aB[t] = (f32x4){0.f, 0.f, 0.f, 0.f};
            #pragma unroll
            for (int ks = 0; ks < 2; ++ks) {
                aT[t] = __builtin_amdgcn_mfma_f32_16x16x32_bf16(At[t][ks], B[ks], aT[t], 0, 0, 0);
                aB[t] = __builtin_amdgcn_mfma_f32_16x16x32_bf16(Ab[t][ks], B[ks], aB[t], 0, 0, 0);
            }
        }

        #pragma unroll
        for (int t = 0; t < 4; ++t)
            #pragma unroll
            for (int r = 0; r < 4; ++r)
                fb[e * 64 + ((16 * t + 4 * g + r) ^ se)] = aT[t][r];
        #pragma unroll
        for (int q = 0; q < 2; ++q) {
            const int row = q * 8 + (lane >> 3);
            const int sr  = ((row & 1) << 4) | ((row >> 1) & 3);
            const int c0  = (lane & 7) * 8;
            uint4 o;
            o.x = pk2h(fb[row * 64 + ((c0 + 0) ^ sr)], fb[row * 64 + ((c0 + 1) ^ sr)]);
            o.y = pk2h(fb[row * 64 + ((c0 + 2) ^ sr)], fb[row * 64 + ((c0 + 3) ^ sr)]);
            o.z = pk2h(fb[row * 64 + ((c0 + 4) ^ sr)], fb[row * 64 + ((c0 + 5) ^ sr)]);
            o.w = pk2h(fb[row * 64 + ((c0 + 6) ^ sr)], fb[row * 64 + ((c0 + 7) ^ sr)]);
            *(uint4*)((char*)Pt + (size_t)tile * 2048 + q * 1024 + lane * 16) = o;
        }

        #pragma unroll
        for (int t = 0; t < 4; ++t)
            #pragma unroll
            for (int r = 0; r < 4; ++r)
                fb[e * 64 + ((16 * t + 4 * g + r) ^ se)] = aB[t][r];
        #pragma unroll
        for (int q = 0; q < 2; ++q) {
            const int row = q * 8 + (lane >> 3);
            const int sr  = ((row & 1) << 4) | ((row >> 1) & 3);
            const int c0  = (lane & 7) * 8;
            uint4 o;
            o.x = pk2h(fb[row * 64 + ((c0 + 0) ^ sr)], fb[row * 64 + ((c0 + 1) ^ sr)]);
            o.y = pk2h(fb[row * 64 + ((c0 + 2) ^ sr)], fb[row * 64 + ((c0 + 3) ^ sr)]);
            o.z = pk2h(fb[row * 64 + ((c0 + 4) ^ sr)], fb[row * 64 + ((c0 + 5) ^ sr)]);
            o.w = pk2h(fb[row * 64 + ((c0 + 6) ^ sr)], fb[row * 64 + ((c0 + 7) ^ sr)]);
            *(uint4*)((char*)Pb + (size_t)tile * 2048 + q * 1024 + lane * 16) = o;
        }
    }
}

// ============ Hierarchical exclusive scan of cnt3[NCNT] -> off3 ============
extern "C" __global__ void __launch_bounds__(1024)
scanA_kernel(const int* __restrict__ cnt3, int* __restrict__ off3, int* __restrict__ bsum)
{
    __shared__ int sh[1024];
    const int t = threadIdx.x;
    const int i = blockIdx.x * 1024 + t;
    const int v = (i < NCNT) ? cnt3[i] : 0;
    sh[t] = v;
    __syncthreads();
    for (int off = 1; off < 1024; off <<= 1) {
        const int u = (t >= off) ? sh[t - off] : 0;
        __syncthreads();
        sh[t] += u;
        __syncthreads();
    }
    if (i < NCNT) off3[i] = sh[t] - v;
    if (t == 1023) bsum[blockIdx.x] = sh[1023];
}

extern "C" __global__ void __launch_bounds__(128)
scanB_kernel(int* __restrict__ bsum)
{
    __shared__ int sh[128];
    const int t = threadIdx.x;
    const int v = (t < SCANB2) ? bsum[t] : 0;
    sh[t] = v;
    __syncthreads();
    for (int off = 1; off < 128; off <<= 1) {
        const int u = (t >= off) ? sh[t - off] : 0;
        __syncthreads();
        sh[t] += u;
        __syncthreads();
    }
    if (t < SCANB2) bsum[t] = sh[t] - v;
}

extern "C" __global__ void __launch_bounds__(1024)
scanC_kernel(int* __restrict__ off3, const int* __restrict__ bsum)
{
    const int i = blockIdx.x * 1024 + threadIdx.x;
    if (i < NCNT) off3[i] += bsum[blockIdx.x];
}

// ============ Privatized scatter: LDS cursors, zero global atomics ============
extern "C" __global__ void __launch_bounds__(1024)
scatter3_kernel(const int* __restrict__ ei, const int* __restrict__ off3,
                unsigned* __restrict__ sedge)
{
    __shared__ int cur[NB];
    const int b   = blockIdx.x;                  // grid must be NBLK
    const int tid = threadIdx.x;
    for (int k = tid; k < NB; k += 1024) cur[k] = off3[k * NBLK + b];
    __syncthreads();
    const int i0 = b * EPB;
    for (int i = i0 + tid; i < i0 + EPB; i += 1024) {
        const int s = ei[i];
        const int d = ei[NE + i];
        const int pos = atomicAdd(&cur[d >> GSH], 1);   // LDS atomic
        sedge[pos] = (unsigned)s | ((unsigned)(d & (GSZ - 1)) << 17);
    }
}

// ============ Per-bucket exact refinement sort ============
extern "C" __global__ void __launch_bounds__(256)
sort2_kernel(const unsigned* __restrict__ sedge, const int* __restrict__ off3,
             int2* __restrict__ spair)
{
    __shared__ int hist[GSZ], base[GSZ], curs[GSZ];
    const int tid = threadIdx.x;
    const int b   = blockIdx.x;
    const int r0  = off3[b * NBLK];
    const int r1  = (b == NB - 1) ? NE : off3[(b + 1) * NBLK];

    if (tid < GSZ) hist[tid] = 0;
    __syncthreads();
    for (int i = r0 + tid; i < r1; i += 256)
        atomicAdd(&hist[(sedge[i] >> 17) & (GSZ - 1)], 1);
    __syncthreads();
    if (tid == 0) {
        int run = 0;
        for (int j = 0; j < GSZ; ++j) { base[j] = run; run += hist[j]; }
    }
    __syncthreads();
    if (tid < GSZ) curs[tid] = base[tid];
    __syncthreads();
    for (int i = r0 + tid; i < r1; i += 256) {
        const unsigned pk = sedge[i];
        const int dl = (pk >> 17) & (GSZ - 1);
        const int pos = r0 + atomicAdd(&curs[dl], 1);
        spair[pos] = make_int2((int)(pk & 0x1FFFFu), (b << GSH) | dl);
    }
}

// ============ Edge kernel (sorted): register-run accumulation, fp16 P ====
// LDS transpose buffer stride = 72 words: b128 writes uniform across banks
// (start = (8e+16t+4g)%32, 8 words/bank = minimum), reads 2-way (free),
// natural channel order (no register permute, no read swizzle).
extern "C" __global__ void __launch_bounds__(256, 2)
edge_kernel_sorted(const unsigned short* __restrict__ Pt, const unsigned short* __restrict__ Pb,
                   const float* __restrict__ x, const int2* __restrict__ spair,
                   const float* __restrict__ We2, const float* __restrict__ be2,
                   const float* __restrict__ Winf, const float* __restrict__ binf,
                   float* __restrict__ mi)
{
    __shared__ float fx[4][16 * FSTR];   // 18 KB
    const int tid  = threadIdx.x;
    const int wib  = tid >> 6;
    const int lane = tid & 63;
    const int e = lane & 15, g = lane >> 4;
    float* fb = &fx[wib][0];

    bf16x8 A2[4][2];                        // fp16 fragments (8 halves / 4 VGPRs)
    f32x4 b2r[4], wir[4];
    #pragma unroll
    for (int t = 0; t < 4; ++t) {
        #pragma unroll
        for (int ks = 0; ks < 2; ++ks) {
            bf16x8 a;
            #pragma unroll
            for (int j = 0; j < 8; ++j)
                a[j] = f2h(We2[(32 * ks + 8 * g + j) * 64 + 16 * t + e]);
            A2[t][ks] = a;
        }
        #pragma unroll
        for (int r = 0; r < 4; ++r) {
            b2r[t][r] = be2[16 * t + 4 * g + r];
            wir[t][r] = Winf[16 * t + 4 * g + r];
        }
    }
    const float binf0 = binf[0];

    const int NT     = NE / 16;
    const int nwaves = gridDim.x * 4;
    const int gwid   = blockIdx.x * 4 + wib;
    const int chunk  = (NT + nwaves - 1) / nwaves;
    const int t0 = gwid * chunk;
    const int t1 = (t0 + chunk < NT) ? t0 + chunk : NT;

    float racc  = 0.f;   // running row accumulator, channel = lane
    int   rrow  = -1;    // wave-uniform current node id

    for (int tile = t0; tile < t1; ++tile) {
        const int eid = tile * 16 + e;
        const int2 sd = spair[eid];
        const int sN = sd.x;
        const int dN = sd.y;

        const float dx = x[dN * 3 + 0] - x[sN * 3 + 0];
        const float dy = x[dN * 3 + 1] - x[sN * 3 + 1];
        const float dz = x[dN * 3 + 2] - x[sN * 3 + 2];
        const float dsq = dx * dx + dy * dy + dz * dz;
        const float edis = sigmoidf_(TEMP / (sqrtf(dsq) + 1e-8f));

        // B2 frags: relu(Pt[dst] + Pb[src]) in packed fp16 (1 pk_add + 3-op relu / pair)
        bf16x8 B2[2];
        #pragma unroll
        for (int ks = 0; ks < 2; ++ks) {
            const uint4 ut = *(const uint4*)(Pt + (size_t)dN * 64 + 32 * ks + 8 * g);
            const uint4 ub = *(const uint4*)(Pb + (size_t)sN * 64 + 32 * ks + 8 * g);
            union { uint4 u; bf16x8 b; } cvt;
            cvt.u.x = pk_add_relu(ut.x, ub.x);
            cvt.u.y = pk_add_relu(ut.y, ub.y);
            cvt.u.z = pk_add_relu(ut.z, ub.z);
            cvt.u.w = pk_add_relu(ut.w, ub.w);
            B2[ks] = cvt.b;
        }

        f32x4 acc2[4];
        #pragma unroll
        for (int t = 0; t < 4; ++t) {
            acc2[t] = b2r[t];
            #pragma unroll
            for (int ks = 0; ks < 2; ++ks)
                acc2[t] = __builtin_amdgcn_mfma_f32_16x16x32_f16(A2[t][ks], B2[ks], acc2[t], 0, 0, 0);
        }

        float m[4][4];
        float p = 0.f;
        #pragma unroll
        for (int t = 0; t < 4; ++t)
            #pragma unroll
            for (int r = 0; r < 4; ++r) {
                m[t][r] = fmaxf(acc2[t][r], 0.f);
                p = fmaf(m[t][r], wir[t][r], p);
            }
        p += __shfl_xor(p, 16);
        p += __shfl_xor(p, 32);
        const float w = sigmoidf_((p + binf0) * edis);

        // transpose via 4x ds_write_b128, natural channel order, stride-72 rows
        #pragma unroll
        for (int t = 0; t < 4; ++t) {
            float4 v;
            v.x = m[t][0] * w; v.y = m[t][1] * w;
            v.z = m[t][2] * w; v.w = m[t][3] * w;
            *(float4*)&fb[e * FSTR + 16 * t + 4 * g] = v;
        }

        #pragma unroll
        for (int i = 0; i < 16; ++i) {
            const int row = __builtin_amdgcn_readlane(dN, i);
            const float v = fb[i * FSTR + lane];
            if (row != rrow) {
                if (rrow >= 0) atomicAdd(mi + (size_t)rrow * 64 + lane, racc);
                rrow = row; racc = v;
            } else {
                racc += v;
            }
        }
    }
    if (rrow >= 0) atomicAdd(mi + (size_t)rrow * 64 + lane, racc);
}

// ============ Edge kernel (unsorted fallback, small-ws path) ============
extern "C" __global__ void __launch_bounds__(256, 2)
edge_kernel_unsorted(const unsigned short* __restrict__ Pt, const unsigned short* __restrict__ Pb,
                     const float* __restrict__ x, const int* __restrict__ ei,
                     const float* __restrict__ We2, const float* __restrict__ be2,
                     const float* __restrict__ Winf, const float* __restrict__ binf,
                     float* __restrict__ mi)
{
    __shared__ float fx[4][16 * FSTR];
    const int tid  = threadIdx.x;
    const int wib  = tid >> 6;
    const int lane = tid & 63;
    const int e = lane & 15, g = lane >> 4;
    float* fb = &fx[wib][0];

    bf16x8 A2[4][2];
    f32x4 b2r[4], wir[4];
    #pragma unroll
    for (int t = 0; t < 4; ++t) {
        #pragma unroll
        for (int ks = 0; ks < 2; ++ks) {
            bf16x8 a;
            #pragma unroll
            for (int j = 0; j < 8; ++j)
                a[j] = f2h(We2[(32 * ks + 8 * g + j) * 64 + 16 * t + e]);
            A2[t][ks] = a;
        }
        #pragma unroll
        for (int r = 0; r < 4; ++r) {
            b2r[t][r] = be2[16 * t + 4 * g + r];
            wir[t][r] = Winf[16 * t + 4 * g + r];
        }
    }
    const float binf0 = binf[0];

    const int gwid = blockIdx.x * 4 + wib;
    const int nw   = gridDim.x * 4;

    for (int tile = gwid; tile < NE / 16; tile += nw) {
        const int eid = tile * 16 + e;
        const int sN = ei[eid];
        const int dN = ei[NE + eid];

        const float dx = x[dN * 3 + 0] - x[sN * 3 + 0];
        const float dy = x[dN * 3 + 1] - x[sN * 3 + 1];
        const float dz = x[dN * 3 + 2] - x[sN * 3 + 2];
        const float dsq = dx * dx + dy * dy + dz * dz;
        const float edis = sigmoidf_(TEMP / (sqrtf(dsq) + 1e-8f));

        bf16x8 B2[2];
        #pragma unroll
        for (int ks = 0; ks < 2; ++ks) {
            const uint4 ut = *(const uint4*)(Pt + (size_t)dN * 64 + 32 * ks + 8 * g);
            const uint4 ub = *(const uint4*)(Pb + (size_t)sN * 64 + 32 * ks + 8 * g);
            union { uint4 u; bf16x8 b; } cvt;
            cvt.u.x = pk_add_relu(ut.x, ub.x);
            cvt.u.y = pk_add_relu(ut.y, ub.y);
            cvt.u.z = pk_add_relu(ut.z, ub.z);
            cvt.u.w = pk_add_relu(ut.w, ub.w);
            B2[ks] = cvt.b;
        }

        f32x4 acc2[4];
        #pragma unroll
        for (int t = 0; t < 4; ++t) {
            acc2[t] = b2r[t];
            #pragma unroll
            for (int ks = 0; ks < 2; ++ks)
                acc2[t] = __builtin_amdgcn_mfma_f32_16x16x32_f16(A2[t][ks], B2[ks], acc2[t], 0, 0, 0);
        }

        float m[4][4];
        float p = 0.f;
        #pragma unroll
        for (int t = 0; t < 4; ++t)
            #pragma unroll
            for (int r = 0; r < 4; ++r) {
                m[t][r] = fmaxf(acc2[t][r], 0.f);
                p = fmaf(m[t][r], wir[t][r], p);
            }
        p += __shfl_xor(p, 16);
        p += __shfl_xor(p, 32);
        const float w = sigmoidf_((p + binf0) * edis);

        #pragma unroll
        for (int t = 0; t < 4; ++t) {
            float4 v;
            v.x = m[t][0] * w; v.y = m[t][1] * w;
            v.z = m[t][2] * w; v.w = m[t][3] * w;
            *(float4*)&fb[e * FSTR + 16 * t + 4 * g] = v;
        }

        #pragma unroll
        for (int i = 0; i < 16; ++i) {
            const int row = __shfl(dN, i);
            const float v = fb[i * FSTR + lane];
            atomicAdd(mi + (size_t)row * 64 + lane, v);
        }
    }
}

// ============ Node kernel: same B2B MFMA + residual + LayerNorm =============
extern "C" __global__ void __launch_bounds__(256, 2)
node_kernel(const float* __restrict__ h, const float* __restrict__ mi_,
            const float* __restrict__ Wn1, const float* __restrict__ bn1,
            const float* __restrict__ Wn2, const float* __restrict__ bn2,
            const float* __restrict__ lng, const float* __restrict__ lnb,
            float* __restrict__ out)
{
    __shared__ unsigned xlds[4][16 * 32];
    const int tid  = threadIdx.x;
    const int wib  = tid >> 6;
    const int lane = tid & 63;
    const int e = lane & 15, g = lane >> 4;
    unsigned* tb = &xlds[wib][0];
    const int sw = (e & 7) << 2;

    bf16x8 A1[4][4], A2[4][2];
    f32x4 b1r[4], b2r[4], gr[4], br[4];
    #pragma unroll
    for (int t = 0; t < 4; ++t) {
        #pragma unroll
        for (int ks = 0; ks < 4; ++ks) {
            bf16x8 a;
            #pragma unroll
            for (int j = 0; j < 8; ++j)
                a[j] = f2bf(Wn1[(32 * ks + 8 * g + j) * 64 + 16 * t + e]);
            A1[t][ks] = a;
        }
        #pragma unroll
        for (int ks = 0; ks < 2; ++ks) {
            bf16x8 a;
            #pragma unroll
            for (int j = 0; j < 8; ++j)
                a[j] = f2bf(Wn2[(32 * ks + 8 * g + j) * 64 + 16 * t + e]);
            A2[t][ks] = a;
        }
        #pragma unroll
        for (int r = 0; r < 4; ++r) {
            b1r[t][r] = bn1[16 * t + 4 * g + r];
            b2r[t][r] = bn2[16 * t + 4 * g + r];
            gr[t][r]  = lng[16 * t + 4 * g + r];
            br[t][r]  = lnb[16 * t + 4 * g + r];
        }
    }

    const int gwid = blockIdx.x * 4 + wib;
    const int nw   = gridDim.x * 4;

    for (int tile = gwid; tile < NN / 16; tile += nw) {
        const int node = tile * 16 + e;

        bf16x8 B1[4];
        #pragma unroll
        for (int ks = 0; ks < 4; ++ks) {
            const float* srcp = (ks < 2) ? mi_ : h;
            const float4* p = (const float4*)(srcp + (size_t)node * 64 + (ks & 1) * 32 + 8 * g);
            const float4 f0 = p[0], f1 = p[1];
            bf16x8 b;
            b[0] = f2bf(f0.x); b[1] = f2bf(f0.y); b[2] = f2bf(f0.z); b[3] = f2bf(f0.w);
            b[4] = f2bf(f1.x); b[5] = f2bf(f1.y); b[6] = f2bf(f1.z); b[7] = f2bf(f1.w);
            B1[ks] = b;
        }

        f32x4 acc1[4];
        #pragma unroll
        for (int t = 0; t < 4; ++t) {
            acc1[t] = b1r[t];
            #pragma unroll
            for (int ks = 0; ks < 4; ++ks)
                acc1[t] = __builtin_amdgcn_mfma_f32_16x16x32_bf16(A1[t][ks], B1[ks], acc1[t], 0, 0, 0);
        }

        #pragma unroll
        for (int t = 0; t < 4; ++t) {
            const float r0 = fmaxf(acc1[t][0], 0.f), r1 = fmaxf(acc1[t][1], 0.f);
            const float r2 = fmaxf(acc1[t][2], 0.f), r3 = fmaxf(acc1[t][3], 0.f);
            tb[e * 32 + ((8 * t + 2 * g + 0) ^ sw)] = pk2(r0, r1);
            tb[e * 32 + ((8 * t + 2 * g + 1) ^ sw)] = pk2(r2, r3);
        }
        bf16x8 B2[2];
        #pragma unroll
        for (int ks = 0; ks < 2; ++ks) {
            union { uint4 u; bf16x8 b; } cvt;
            cvt.u = *(const uint4*)&tb[e * 32 + ((16 * ks + 4 * g) ^ sw)];
            B2[ks] = cvt.b;
        }

        f32x4 acc2[4];
        #pragma unroll
        for (int t = 0; t < 4; ++t) {
            acc2[t] = b2r[t];
            #pragma unroll
            for (int ks = 0; ks < 2; ++ks)
                acc2[t] = __builtin_amdgcn_mfma_f32_16x16x32_bf16(A2[t][ks], B2[ks], acc2[t], 0, 0, 0);
        }

        float z[4][4];
        float s1 = 0.f, s2 = 0.f;
        #pragma unroll
        for (int t = 0; t < 4; ++t) {
            const float4 hres = *(const float4*)(h + (size_t)node * 64 + 16 * t + 4 * g);
            #pragma unroll
            for (int r = 0; r < 4; ++r) {
                z[t][r] = acc2[t][r] + hres[r];
                s1 += z[t][r];
                s2 = fmaf(z[t][r], z[t][r], s2);
            }
        }
        s1 += __shfl_xor(s1, 16); s1 += __shfl_xor(s1, 32);
        s2 += __shfl_xor(s2, 16); s2 += __shfl_xor(s2, 32);
        const float mu   = s1 * (1.0f / 64.0f);
        const float var  = s2 * (1.0f / 64.0f) - mu * mu;
        const float rstd = rsqrtf(var + LNEPS);

        #pragma unroll
        for (int t = 0; t < 4; ++t) {
            float4 o;
            #pragma unroll
            for (int r = 0; r < 4; ++r)
                o[r] = (z[t][r] - mu) * rstd * gr[t][r] + br[t][r];
            *(float4*)(out + (size_t)node * 64 + 16 * t + 4 * g) = o;
        }
    }
}

extern "C" void kernel_launch(void* const* d_in, const int* in_sizes, int n_in,
                              void* d_out, int out_size, void* d_ws, size_t ws_size,
                              hipStream_t stream)
{
    const float* h    = (const float*)d_in[0];
    const float* x    = (const float*)d_in[1];
    const int*   ei   = (const int*)d_in[2];
    const float* We1  = (const float*)d_in[3];
    const float* be1  = (const float*)d_in[4];
    const float* We2  = (const float*)d_in[5];
    const float* be2  = (const float*)d_in[6];
    const float* Winf = (const float*)d_in[7];
    const float* binf = (const float*)d_in[8];
    const float* Wn1  = (const float*)d_in[9];
    const float* bn1  = (const float*)d_in[10];
    const float* Wn2  = (const float*)d_in[11];
    const float* bn2  = (const float*)d_in[12];
    const float* lng  = (const float*)d_in[13];
    const float* lnb  = (const float*)d_in[14];
    float* out = (float*)d_out;

    const size_t mi_bytes = (size_t)NN * HDIM * sizeof(float);          // 25.6 MB
    const size_t p_bytes  = (size_t)NN * HDIM * sizeof(unsigned short); // 12.8 MB
    const size_t sp_bytes = (size_t)NE * sizeof(int2);                  // 12.8 MB
    const size_t se_bytes = (size_t)NE * sizeof(unsigned);              //  6.4 MB
    const size_t c3_bytes = (size_t)NCNT * sizeof(int);                 //  0.4 MB

    // sedge/cnt3/off3/bsum all alias mi's scratch (dead before memset(mi))
    const size_t need_sorted = mi_bytes + 2 * p_bytes + sp_bytes;

    if (ws_size >= need_sorted &&
        mi_bytes >= se_bytes + 2 * c3_bytes + SCANB2 * sizeof(int)) {
        char* ws = (char*)d_ws;
        float*          mi    = (float*)ws;              ws += mi_bytes;
        unsigned short* Pt    = (unsigned short*)ws;     ws += p_bytes;
        unsigned short* Pb    = (unsigned short*)ws;     ws += p_bytes;
        int2*           spair = (int2*)ws;

        char* mis = (char*)mi;
        unsigned* sedge = (unsigned*)mis;                          // [0, 6.4 MB)
        int*      cnt3  = (int*)(mis + se_bytes);                  // 0.4 MB
        int*      off3  = (int*)(mis + se_bytes + c3_bytes);       // 0.4 MB
        int*      bsum  = (int*)(mis + se_bytes + 2 * c3_bytes);   // 392 B

        hipMemcpyAsync(out + (size_t)NN * HDIM, x, (size_t)NN * 3 * sizeof(float),
                       hipMemcpyDeviceToDevice, stream);

        front_kernel<<<NBLK + 512, 256, 0, stream>>>(h, We1, be1, Pt, Pb, ei, cnt3);
        scanA_kernel<<<SCANB2, 1024, 0, stream>>>(cnt3, off3, bsum);
        scanB_kernel<<<1, 128, 0, stream>>>(bsum);
        scanC_kernel<<<SCANB2, 1024, 0, stream>>>(off3, bsum);
        scatter3_kernel<<<NBLK, 1024, 0, stream>>>(ei, off3, sedge);
        sort2_kernel<<<NB, 256, 0, stream>>>(sedge, off3, spair);
        hipMemsetAsync(mi, 0, mi_bytes, stream);   // after sort2: frees aliases
        edge_kernel_sorted<<<2048, 256, 0, stream>>>(Pt, Pb, x, spair, We2, be2, Winf, binf, mi);
        node_kernel<<<512, 256, 0, stream>>>(h, mi, Wn1, bn1, Wn2, bn2, lng, lnb, out);
    } else {
        float* mi;
        unsigned short* Pt;
        unsigned short* Pb;
        if (ws_size >= mi_bytes + 2 * p_bytes) {
            mi = (float*)d_ws;
            Pt = (unsigned short*)((char*)d_ws + mi_bytes);
            Pb = (unsigned short*)((char*)d_ws + mi_bytes + p_bytes);
        } else {
            mi = out;
            Pt = (unsigned short*)d_ws;
            Pb = (unsigned short*)((char*)d_ws + p_bytes);
        }

        hipMemsetAsync(mi, 0, mi_bytes, stream);
        hipMemcpyAsync(out + (size_t)NN * HDIM, x, (size_t)NN * 3 * sizeof(float),
                       hipMemcpyDeviceToDevice, stream);

        front_kernel<<<NBLK + 512, 256, 0, stream>>>(h, We1, be1, Pt, Pb, ei,
                                                     (int*)((char*)d_ws));  // cnt3 scratch unused later
        edge_kernel_unsorted<<<2048, 256, 0, stream>>>(Pt, Pb, x, ei, We2, be2, Winf, binf, mi);
        node_kernel<<<512, 256, 0, stream>>>(h, mi, Wn1, bn1, Wn2, bn2, lng, lnb, out);
    }
}